// Round 15
// baseline (4549.078 us; speedup 1.0000x reference)
//
#include <hip/hip_runtime.h>
#include <hip/hip_bf16.h>

#define H1 1024
#define FOURH 4096
#define BATCH 512
#define SEQ 64
#define DIN 128
#define TDEC 8
#define SCR 68

typedef float f32x4 __attribute__((ext_vector_type(4)));
typedef __bf16 bf16x8 __attribute__((ext_vector_type(8)));

// global->LDS direct, 16B per lane. LDS dest is wave-uniform base + lane*16.
__device__ __forceinline__ void gl_lds16(const void* g, void* l) {
    __builtin_amdgcn_global_load_lds(
        (const __attribute__((address_space(1))) unsigned int*)g,
        (__attribute__((address_space(3))) unsigned int*)l, 16, 0, 0);
}

// ---------------------------------------------------------------------------
// Weights [4096][K] f32 -> permuted interleaved-pair bf16.
// dst row dr = uc*64 + c  (uc 0..63, c 0..63; unit = uc*16 + (c>>2), gate=c&3,
// src row r = gate*1024 + unit). Row layout: K/32 blocks of 128B =
// [hi(32 elems) 64B | lo(32 elems) 64B]  -> row bytes = 4K, same as f32 row.
// ---------------------------------------------------------------------------
__global__ __launch_bounds__(256) void conv_wpair_k(
    const float* __restrict__ src, __bf16* __restrict__ dst, int K, int ks5)
{
    int i = blockIdx.x * 256 + threadIdx.x;          // piece = 8 elems
    int c  = i & 63;
    int g  = (i >> 6) & 3;
    int t  = (i >> 8) & 1;
    int kk = (i >> 9) & ((1 << ks5) - 1);
    int uc = i >> (9 + ks5);
    int r  = (c & 3) * 1024 + uc * 16 + (c >> 2);
    const float* s = src + (size_t)r * K + kk * 32 + g * 8;
    bf16x8 p;
#pragma unroll
    for (int e = 0; e < 8; ++e) {
        float v = s[e];
        __bf16 h = (__bf16)v;
        p[e] = t ? (__bf16)(v - (float)h) : h;
    }
    int dr = uc * 64 + c;
    *(bf16x8*)(dst + (size_t)dr * 2 * K + kk * 64 + t * 32 + g * 8) = p;
}

// ---------------------------------------------------------------------------
// Fused GEMM + LSTM cell, all-pair all-LDS variant.
// Block = 64 batch x 64 gate-cols (16 units). grid 512 = 8 bm x 64 uc
// (wg%8 = uc%8 -> B-sharing blocks on one XCD). 4 waves (2m x 2n), wave tile
// 32x32 (2x2 frags of 16x16x32), 3-term hi/lo MFMA. 2 blocks/CU (64KB LDS).
// A and B staged via gl_lds16 only. Barrier every TWO chunks.
// SHARER DESYNC: block bm traverses chunks rotated by off = bm*(n/8 rounded
// even) so the 8 bm-sharers of a B-panel request DIFFERENT lines concurrently
// (8x unique-miss parallelism; r14 counters showed unique-fetch-rate bound).
// Operand rows are interleaved-pair (128B per 32-k: hi64|lo64) — byte-
// compatible with f32 rows, so layer-0's x segment stays f32 and is split
// in-register (a0f32 chunks, physical idx < nA). Cell epilogue in-block;
// h out as interleaved pair.
// ---------------------------------------------------------------------------
__global__ __launch_bounds__(256, 2) void lstm_fb2(
    const char* __restrict__ a0, long long a0row_b, int k0, int a0f32,
    const char* __restrict__ a1,                     // h pair, row 4096B
    const __bf16* __restrict__ w0p,                  // permuted pair, row 4*k0 B
    const __bf16* __restrict__ w1p,                  // permuted pair, row 4096B
    const float* __restrict__ bias,
    float* __restrict__ cst, __bf16* __restrict__ hout)
{
    __shared__ char smem[65536];                     // 4 bufs x (A 8KB + B 8KB)
    const int tid  = threadIdx.x;
    const int lane = tid & 63;
    const int w    = tid >> 6;                       // wave 0..3
    const int wm   = w >> 1, wn = w & 1;
    const int wg   = blockIdx.x;
    const int bm   = wg >> 6;                        // 0..7
    const int uc   = wg & 63;                        // 0..63

    const int nA = k0 >> 5;
    const int n  = nA + 32;                          // even for all layers
    const int off = bm * ((n >> 3) & ~1);            // even rotation offset

    // ---- staging geometry: 4 gl_lds16 per wave per chunk (A 2 + B 2) ----
    const int rsub = lane >> 3;
    const int slot = lane & 7;
    const int gsw  = slot ^ rsub;                    // XOR-swizzled src granule

    const char* paj0[2]; const char* paj1[2];
    const char* pbj0[2]; const char* pbj1[2];
#pragma unroll
    for (int j = 0; j < 2; ++j) {
        int ar = bm * 64 + w * 16 + j * 8 + rsub;
        paj0[j] = a0 + (size_t)ar * a0row_b + gsw * 16;
        paj1[j] = a1 + (size_t)ar * 4096 + gsw * 16;
        int c  = w * 16 + j * 8 + rsub;              // B row (gate-col)
        int dr = uc * 64 + c;
        pbj0[j] = (const char*)w0p + (size_t)dr * (4 * (size_t)k0) + gsw * 16;
        pbj1[j] = (const char*)w1p + (size_t)dr * 4096 + gsw * 16;
    }

    // LDS dests are wave-uniform (HW adds lane*16): wave w, sub-block j
    // covers LDS rows w*16+j*8 .. +8 (8 rows x 128B = 1024B per gl_lds16).
    auto stage = [&](int phys, int buf) {
        char* bufA = smem + buf * 16384;
        char* bufB = bufA + 8192;
        if (phys < nA) {
            size_t kb = (size_t)phys * 128;
#pragma unroll
            for (int j = 0; j < 2; ++j) {
                gl_lds16(paj0[j] + kb, bufA + w * 2048 + j * 1024);
                gl_lds16(pbj0[j] + kb, bufB + w * 2048 + j * 1024);
            }
        } else {
            size_t kb = (size_t)(phys - nA) * 128;
#pragma unroll
            for (int j = 0; j < 2; ++j) {
                gl_lds16(paj1[j] + kb, bufA + w * 2048 + j * 1024);
                gl_lds16(pbj1[j] + kb, bufB + w * 2048 + j * 1024);
            }
        }
    };

    // ---- fragment geometry ----
    int rA[2], rB[2];
#pragma unroll
    for (int f = 0; f < 2; ++f) {
        rA[f] = wm * 32 + f * 16 + (lane & 15);
        rB[f] = wn * 32 + f * 16 + (lane & 15);
    }
    const int s7 = lane & 7;
    const int g0 = lane >> 4;                        // k-granule group 0..3

    f32x4 acc[2][2];
#pragma unroll
    for (int a = 0; a < 2; ++a)
#pragma unroll
        for (int b = 0; b < 2; ++b)
            acc[a][b] = (f32x4){0.f, 0.f, 0.f, 0.f};

    auto chunk = [&](int phys, int buf) {
        char* bufA = smem + buf * 16384;
        char* bufB = bufA + 8192;
        bf16x8 ah[2], al[2], bh[2], bl[2];
        if (a0f32 && phys < nA) {                    // layer-0 x chunks only
#pragma unroll
            for (int f = 0; f < 2; ++f) {
                f32x4 v0 = *(const f32x4*)(bufA + rA[f] * 128 + ((2 * g0    ) ^ s7) * 16);
                f32x4 v1 = *(const f32x4*)(bufA + rA[f] * 128 + ((2 * g0 + 1) ^ s7) * 16);
#pragma unroll
                for (int e = 0; e < 4; ++e) {
                    __bf16 h0 = (__bf16)v0[e];
                    ah[f][e] = h0; al[f][e] = (__bf16)(v0[e] - (float)h0);
                    __bf16 h1 = (__bf16)v1[e];
                    ah[f][e + 4] = h1; al[f][e + 4] = (__bf16)(v1[e] - (float)h1);
                }
            }
        } else {
#pragma unroll
            for (int f = 0; f < 2; ++f) {
                ah[f] = *(const bf16x8*)(bufA + rA[f] * 128 + ((g0    ) ^ s7) * 16);
                al[f] = *(const bf16x8*)(bufA + rA[f] * 128 + ((g0 + 4) ^ s7) * 16);
            }
        }
#pragma unroll
        for (int f = 0; f < 2; ++f) {
            bh[f] = *(const bf16x8*)(bufB + rB[f] * 128 + ((g0    ) ^ s7) * 16);
            bl[f] = *(const bf16x8*)(bufB + rB[f] * 128 + ((g0 + 4) ^ s7) * 16);
        }
#pragma unroll
        for (int mf = 0; mf < 2; ++mf)
#pragma unroll
            for (int nf = 0; nf < 2; ++nf) {
                acc[mf][nf] = __builtin_amdgcn_mfma_f32_16x16x32_bf16(
                    ah[mf], bh[nf], acc[mf][nf], 0, 0, 0);
                acc[mf][nf] = __builtin_amdgcn_mfma_f32_16x16x32_bf16(
                    ah[mf], bl[nf], acc[mf][nf], 0, 0, 0);
                acc[mf][nf] = __builtin_amdgcn_mfma_f32_16x16x32_bf16(
                    al[mf], bh[nf], acc[mf][nf], 0, 0, 0);
            }
    };

    // prologue: first interval's chunks (physical = off, off+1)
    stage(off, 0);
    stage(off + 1, 1);

    for (int p = 0; p < n; p += 2) {
        asm volatile("s_waitcnt vmcnt(0)" ::: "memory");
        __builtin_amdgcn_sched_barrier(0);
        __builtin_amdgcn_s_barrier();
        __builtin_amdgcn_sched_barrier(0);

        if (p + 2 < n) {                             // bufs freed last interval
            int q = p + 2 + off; if (q >= n) q -= n; // q even -> q+1 in range
            stage(q,     (p + 2) & 3);
            stage(q + 1, (p + 3) & 3);
        }

        int c0 = p + off; if (c0 >= n) c0 -= n;      // c0 even
        chunk(c0,     p & 3);
        chunk(c0 + 1, (p + 1) & 3);
        __builtin_amdgcn_sched_barrier(0);
    }

    // ---- epilogue: acc -> LDS scratch [64][SCR] f32 ----
    __syncthreads();
    float* scr = (float*)smem;
#pragma unroll
    for (int mf = 0; mf < 2; ++mf)
#pragma unroll
        for (int nf = 0; nf < 2; ++nf) {
            int row0 = wm * 32 + mf * 16 + (lane >> 4) * 4;   // m89 C layout
            int col  = wn * 32 + nf * 16 + (lane & 15);
#pragma unroll
            for (int j = 0; j < 4; ++j)
                scr[(row0 + j) * SCR + col] = acc[mf][nf][j];
        }
    __syncthreads();

    // ---- in-block cell: 64 rows x 16 units ----
#pragma unroll
    for (int p = 0; p < 4; ++p) {
        int item = p * 256 + tid;
        int u = item & 15;
        int r = item >> 4;                           // 0..63
        f32x4 g4 = *(const f32x4*)(scr + r * SCR + u * 4);
        int gu = uc * 16 + u;
        float gi = g4[0] + bias[gu];
        float gf = g4[1] + bias[H1 + gu];
        float gg = g4[2] + bias[2 * H1 + gu];
        float go = g4[3] + bias[3 * H1 + gu];
        float si = 1.f / (1.f + expf(-gi));
        float sf = 1.f / (1.f + expf(-gf));
        float so = 1.f / (1.f + expf(-go));
        int row_g = bm * 64 + r;
        size_t ci = (size_t)row_g * H1 + gu;
        float cc = sf * cst[ci] + si * tanhf(gg);
        cst[ci] = cc;
        float hv = so * tanhf(cc);
        __bf16 hh = (__bf16)hv;
        size_t hb = (size_t)row_g * 2048 + (gu >> 5) * 64 + (gu & 31);
        hout[hb]      = hh;
        hout[hb + 32] = (__bf16)(hv - (float)hh);
    }
}

// ---------------------------------------------------------------------------
// head on interleaved-pair h — wave-parallel: 16 lanes per output, shfl_xor
// reduce. grid 512 x 256 threads = 16 outputs/block.
// ---------------------------------------------------------------------------
__global__ __launch_bounds__(256) void head_pair2_k(
    const __bf16* __restrict__ hp, const float* __restrict__ W,
    const float* __restrict__ bo, float* __restrict__ out)
{
    int gid  = blockIdx.x * 16 + (threadIdx.x >> 4); // output 0..8191
    int l16  = threadIdx.x & 15;
    int b = gid >> 4, o = gid & 15;
    const __bf16* hr = hp + (size_t)b * 2048 + l16 * 128;  // 2 unit-blocks
    const float*  wr = W + (size_t)o * H1 + l16 * 64;
    float s = 0.f;
#pragma unroll
    for (int q = 0; q < 2; ++q) {
#pragma unroll
        for (int r = 0; r < 4; ++r) {
            bf16x8 vh = *(const bf16x8*)(hr + q * 64 + r * 8);
            bf16x8 vl = *(const bf16x8*)(hr + q * 64 + 32 + r * 8);
            const f32x4* wv = (const f32x4*)(wr + q * 32 + r * 8);
            f32x4 w0 = wv[0], w1 = wv[1];
#pragma unroll
            for (int e = 0; e < 4; ++e)
                s += ((float)vh[e] + (float)vl[e]) * w0[e];
#pragma unroll
            for (int e = 4; e < 8; ++e)
                s += ((float)vh[e] + (float)vl[e]) * w1[e - 4];
        }
    }
#pragma unroll
    for (int m = 8; m >= 1; m >>= 1)
        s += __shfl_xor(s, m, 16);
    if (l16 == 0) {
        float v = s + bo[o];
        out[(size_t)b * 32 + o]      = v;
        out[(size_t)b * 32 + 16 + o] = v;
    }
}

// ---------------------------------------------------------------------------
// FALLBACK (r9/r10-proven f32 all-LDS path) — runs only if ws too small.
// ---------------------------------------------------------------------------
__global__ __launch_bounds__(256, 1) void lstm_fused_f32(
    const float* __restrict__ a0v, long long arow_b, int k0,
    const float* __restrict__ w0v,
    const float* __restrict__ a1v,
    const float* __restrict__ w1v,
    const float* __restrict__ bias,
    float* __restrict__ cst, float* __restrict__ houtv)
{
    extern __shared__ char smem[];
    const int tid  = threadIdx.x;
    const int lane = tid & 63;
    const int w    = tid >> 6;
    const int wm   = w >> 1, wn = w & 1;
    const int wg   = blockIdx.x;
    const int bm   = wg >> 5;
    const int uc   = wg & 31;

    const int nA = k0 >> 5;
    const int n  = nA + 32;

    const int rsub = lane >> 3;
    const int slot = lane & 7;
    const int gsw  = slot ^ rsub;

    const char* paj0[2]; const char* paj1[2];
    const char* pbj0[4]; const char* pbj1[4];
#pragma unroll
    for (int j = 0; j < 2; ++j) {
        int ar = bm * 64 + w * 16 + j * 8 + rsub;
        paj0[j] = (const char*)a0v + (size_t)ar * arow_b + gsw * 16;
        paj1[j] = (const char*)a1v + (size_t)ar * 4096 + gsw * 16;
    }
#pragma unroll
    for (int j = 0; j < 4; ++j) {
        int c = w * 32 + j * 8 + rsub;
        int br0 = (c & 3) * H1 + uc * 32 + (c >> 2);
        pbj0[j] = (const char*)w0v + (size_t)br0 * (4 * (size_t)k0) + gsw * 16;
        pbj1[j] = (const char*)w1v + (size_t)br0 * 4096 + gsw * 16;
    }

    auto stage = [&](int ii, int buf) {
        char* bufA = smem + buf * 24576;
        char* bufB = bufA + 8192;
        size_t kb = (ii < nA) ? (size_t)ii * 128 : (size_t)(ii - nA) * 128;
        const char* const* pa = (ii < nA) ? paj0 : paj1;
        const char* const* pb = (ii < nA) ? pbj0 : pbj1;
#pragma unroll
        for (int j = 0; j < 2; ++j)
            gl_lds16(pa[j] + kb, bufA + (w * 2 + j) * 1024);
#pragma unroll
        for (int j = 0; j < 4; ++j)
            gl_lds16(pb[j] + kb, bufB + (w * 4 + j) * 1024);
    };

    int rAv[2], rBv[4];
#pragma unroll
    for (int f = 0; f < 2; ++f) rAv[f] = wm * 32 + f * 16 + (lane & 15);
#pragma unroll
    for (int f = 0; f < 4; ++f) rBv[f] = wn * 64 + f * 16 + (lane & 15);
    const int s7 = lane & 7;
    const int g0 = lane >> 4;

    f32x4 acc[2][4];
#pragma unroll
    for (int mf = 0; mf < 2; ++mf)
#pragma unroll
        for (int nf = 0; nf < 4; ++nf)
            acc[mf][nf] = (f32x4){0.f, 0.f, 0.f, 0.f};

    stage(0, 0); stage(1, 1); stage(2, 2); stage(3, 3); stage(4, 4);

    int buf = 0;
    for (int i = 0; i < n; ++i) {
        const int rem = n - i;
        if (rem >= 5)      asm volatile("s_waitcnt vmcnt(24)" ::: "memory");
        else if (rem == 4) asm volatile("s_waitcnt vmcnt(18)" ::: "memory");
        else if (rem == 3) asm volatile("s_waitcnt vmcnt(12)" ::: "memory");
        else if (rem == 2) asm volatile("s_waitcnt vmcnt(6)"  ::: "memory");
        else               asm volatile("s_waitcnt vmcnt(0)"  ::: "memory");
        __builtin_amdgcn_sched_barrier(0);
        __builtin_amdgcn_s_barrier();
        __builtin_amdgcn_sched_barrier(0);

        if (i + 5 < n) {
            int b5 = buf + 5; if (b5 >= 6) b5 -= 6;
            stage(i + 5, b5);
        }

        char* bufA = smem + buf * 24576;
        char* bufB = bufA + 8192;

        bf16x8 ah[2], al[2], bh[4], bl[4];
#pragma unroll
        for (int f = 0; f < 2; ++f) {
            f32x4 v0 = *(const f32x4*)(bufA + rAv[f] * 128 + ((2 * g0    ) ^ s7) * 16);
            f32x4 v1 = *(const f32x4*)(bufA + rAv[f] * 128 + ((2 * g0 + 1) ^ s7) * 16);
#pragma unroll
            for (int e = 0; e < 4; ++e) {
                __bf16 h0 = (__bf16)v0[e];
                ah[f][e] = h0; al[f][e] = (__bf16)(v0[e] - (float)h0);
                __bf16 h1 = (__bf16)v1[e];
                ah[f][e + 4] = h1; al[f][e + 4] = (__bf16)(v1[e] - (float)h1);
            }
        }
#pragma unroll
        for (int f = 0; f < 4; ++f) {
            f32x4 u0 = *(const f32x4*)(bufB + rBv[f] * 128 + ((2 * g0    ) ^ s7) * 16);
            f32x4 u1 = *(const f32x4*)(bufB + rBv[f] * 128 + ((2 * g0 + 1) ^ s7) * 16);
#pragma unroll
            for (int e = 0; e < 4; ++e) {
                __bf16 h0 = (__bf16)u0[e];
                bh[f][e] = h0; bl[f][e] = (__bf16)(u0[e] - (float)h0);
                __bf16 h1 = (__bf16)u1[e];
                bh[f][e + 4] = h1; bl[f][e + 4] = (__bf16)(u1[e] - (float)h1);
            }
        }
#pragma unroll
        for (int mf = 0; mf < 2; ++mf)
#pragma unroll
            for (int nf = 0; nf < 4; ++nf) {
                acc[mf][nf] = __builtin_amdgcn_mfma_f32_16x16x32_bf16(
                    ah[mf], bh[nf], acc[mf][nf], 0, 0, 0);
                acc[mf][nf] = __builtin_amdgcn_mfma_f32_16x16x32_bf16(
                    ah[mf], bl[nf], acc[mf][nf], 0, 0, 0);
                acc[mf][nf] = __builtin_amdgcn_mfma_f32_16x16x32_bf16(
                    al[mf], bh[nf], acc[mf][nf], 0, 0, 0);
            }
        __builtin_amdgcn_sched_barrier(0);
        buf = buf + 1; if (buf >= 6) buf -= 6;
    }

    __syncthreads();
    float* scr = (float*)smem;
#pragma unroll
    for (int mf = 0; mf < 2; ++mf)
#pragma unroll
        for (int nf = 0; nf < 4; ++nf) {
            int row0 = wm * 32 + mf * 16 + (lane >> 4) * 4;
            int col  = wn * 64 + nf * 16 + (lane & 15);
#pragma unroll
            for (int j = 0; j < 4; ++j)
                scr[(row0 + j) * 128 + col] = acc[mf][nf][j];
        }
    __syncthreads();

#pragma unroll
    for (int p = 0; p < 8; ++p) {
        int item = p * 256 + tid;
        int u = item & 31;
        int r = item >> 5;
        f32x4 g4 = *(const f32x4*)(scr + r * 128 + u * 4);
        int gu = uc * 32 + u;
        float gi = g4[0] + bias[gu];
        float gf = g4[1] + bias[H1 + gu];
        float gg = g4[2] + bias[2 * H1 + gu];
        float go = g4[3] + bias[3 * H1 + gu];
        float si = 1.f / (1.f + expf(-gi));
        float sf = 1.f / (1.f + expf(-gf));
        float so = 1.f / (1.f + expf(-go));
        size_t ci = (size_t)(bm * 64 + r) * H1 + gu;
        float cc = sf * cst[ci] + si * tanhf(gg);
        cst[ci] = cc;
        houtv[ci] = so * tanhf(cc);
    }
}

__global__ __launch_bounds__(256) void head_k(
    const float* __restrict__ h, const float* __restrict__ W,
    const float* __restrict__ bo, float* __restrict__ out)
{
    int idx = blockIdx.x * 256 + threadIdx.x;
    int b = idx >> 4, o = idx & 15;
    const f32x4* hv = (const f32x4*)(h + (size_t)b * H1);
    const f32x4* wv = (const f32x4*)(W + (size_t)o * H1);
    float s = bo[o];
#pragma unroll 4
    for (int k = 0; k < H1 / 4; ++k) {
        f32x4 a = hv[k];
        f32x4 wq = wv[k];
        s += a[0] * wq[0] + a[1] * wq[1] + a[2] * wq[2] + a[3] * wq[3];
    }
    out[(size_t)b * 32 + o]      = s;
    out[(size_t)b * 32 + 16 + o] = s;
}

// ===========================================================================
extern "C" void kernel_launch(void* const* d_in, const int* in_sizes, int n_in,
                              void* d_out, int out_size, void* d_ws, size_t ws_size,
                              hipStream_t stream)
{
    const float* x    = (const float*)d_in[0];
    const float* Wih0 = (const float*)d_in[1];
    const float* Whh0 = (const float*)d_in[2];
    const float* b0   = (const float*)d_in[3];
    const float* Wih1 = (const float*)d_in[4];
    const float* Whh1 = (const float*)d_in[5];
    const float* b1   = (const float*)d_in[6];
    const float* dWih = (const float*)d_in[7];
    const float* dWhh = (const float*)d_in[8];
    const float* db   = (const float*)d_in[9];
    const float* Wout = (const float*)d_in[10];
    const float* bout = (const float*)d_in[11];

    dim3 blk(256);
    const size_t WP_SMALL = (size_t)4096 * 128 * 4;    // 2MB   (K=128 pair)
    const size_t WP_BIG   = (size_t)4096 * 1024 * 4;   // 16MB  (K=1024 pair)
    const size_t HPB      = (size_t)BATCH * 4096;      // 2MB   h pair bytes
    const size_t CSZ      = (size_t)BATCH * H1;        // elems
    const size_t NEED1    = WP_SMALL + 7 * WP_BIG + 4 * HPB + 2 * CSZ * 4;

    const float* dWih1 = dWih + (size_t)FOURH * H1;
    const float* dWhh1 = dWhh + (size_t)FOURH * H1;

    if (ws_size >= NEED1) {
        // ---------------- pair path ----------------
        char* wsb = (char*)d_ws;
        __bf16* Wih0p  = (__bf16*)wsb;
        __bf16* Whh0p  = (__bf16*)(wsb + WP_SMALL);
        __bf16* Wih1p  = (__bf16*)(wsb + WP_SMALL + WP_BIG);
        __bf16* Whh1p  = (__bf16*)(wsb + WP_SMALL + 2 * WP_BIG);
        __bf16* dWih0p = (__bf16*)(wsb + WP_SMALL + 3 * WP_BIG);
        __bf16* dWhh0p = (__bf16*)(wsb + WP_SMALL + 4 * WP_BIG);
        __bf16* dWih1p = (__bf16*)(wsb + WP_SMALL + 5 * WP_BIG);
        __bf16* dWhh1p = (__bf16*)(wsb + WP_SMALL + 6 * WP_BIG);
        char* sb = wsb + WP_SMALL + 7 * WP_BIG;
        __bf16* hp0a = (__bf16*)sb;
        __bf16* hp0b = (__bf16*)(sb + HPB);
        __bf16* hp1a = (__bf16*)(sb + 2 * HPB);
        __bf16* hp1b = (__bf16*)(sb + 3 * HPB);
        float*  c0   = (float*)(sb + 4 * HPB);
        float*  c1   = c0 + CSZ;

        auto convw = [&](const float* s, __bf16* d, int K, int ks5) {
            int total = 32768 * (K >> 5);
            conv_wpair_k<<<dim3(total / 256), blk, 0, stream>>>(s, d, K, ks5);
        };
        convw(Wih0, Wih0p, 128, 2);
        convw(Whh0, Whh0p, 1024, 5);
        convw(Wih1, Wih1p, 1024, 5);
        convw(Whh1, Whh1p, 1024, 5);
        convw(dWih,  dWih0p, 1024, 5);
        convw(dWih1, dWih1p, 1024, 5);
        convw(dWhh,  dWhh0p, 1024, 5);
        convw(dWhh1, dWhh1p, 1024, 5);

        hipMemsetAsync(sb, 0, 4 * HPB + 2 * CSZ * 4, stream);

        dim3 fgrid(512);
        __bf16 *hc = hp0a, *hn = hp0b, *h1c = hp1a, *h1n = hp1b;
        const long long XROW = (long long)(SEQ * DIN * 4);
        for (int t = 0; t < SEQ; ++t) {
            lstm_fb2<<<fgrid, blk, 0, stream>>>(
                (const char*)(x + (size_t)t * DIN), XROW, DIN, 1,
                (const char*)hc, Wih0p, Whh0p, b0, c0, hn);
            lstm_fb2<<<fgrid, blk, 0, stream>>>(
                (const char*)hn, 4096LL, H1, 0,
                (const char*)h1c, Wih1p, Whh1p, b1, c1, h1n);
            __bf16* t0 = hc; hc = hn; hn = t0;
            __bf16* t1 = h1c; h1c = h1n; h1n = t1;
        }
        for (int s = 0; s < TDEC; ++s) {
            lstm_fb2<<<fgrid, blk, 0, stream>>>(
                (const char*)h1c, 4096LL, H1, 0,
                (const char*)hc, dWih0p, dWhh0p, db, c0, hn);
            lstm_fb2<<<fgrid, blk, 0, stream>>>(
                (const char*)hn, 4096LL, H1, 0,
                (const char*)h1c, dWih1p, dWhh1p, db + FOURH, c1, h1n);
            __bf16* t0 = hc; hc = hn; hn = t0;
            __bf16* t1 = h1c; h1c = h1n; h1n = t1;
        }
        head_pair2_k<<<dim3(512), blk, 0, stream>>>(h1c, Wout, bout, (float*)d_out);
    } else {
        // ---------------- f32 fallback (proven) ----------------
        float* h0a = (float*)d_ws;
        float* h0b = h0a + CSZ;
        float* h1a = h0b + CSZ;
        float* h1b = h1a + CSZ;
        float* c0  = h1b + CSZ;
        float* c1  = c0 + CSZ;
        hipMemsetAsync(h0a, 0, 6 * CSZ * 4, stream);

        (void)hipFuncSetAttribute(reinterpret_cast<const void*>(&lstm_fused_f32),
                                  hipFuncAttributeMaxDynamicSharedMemorySize, 147456);

        dim3 oldgrid(256);
        float *hc = h0a, *hn = h0b, *h1c = h1a, *h1n = h1b;
        for (int t = 0; t < SEQ; ++t) {
            lstm_fused_f32<<<oldgrid, blk, 147456, stream>>>(
                x + (size_t)t * DIN, (long long)(SEQ * DIN * 4), DIN, Wih0,
                hc, Whh0, b0, c0, hn);
            lstm_fused_f32<<<oldgrid, blk, 147456, stream>>>(
                hn, 4096LL, H1, Wih1, h1c, Whh1, b1, c1, h1n);
            float* t0 = hc; hc = hn; hn = t0;
            float* t1 = h1c; h1c = h1n; h1n = t1;
        }
        for (int s = 0; s < TDEC; ++s) {
            lstm_fused_f32<<<oldgrid, blk, 147456, stream>>>(
                h1c, 4096LL, H1, dWih, hc, dWhh, db, c0, hn);
            lstm_fused_f32<<<oldgrid, blk, 147456, stream>>>(
                hn, 4096LL, H1, dWih1, h1c, dWhh1, db + FOURH, c1, h1n);
            float* t0 = hc; hc = hn; hn = t0;
            float* t1 = h1c; h1c = h1n; h1n = t1;
        }
        head_k<<<dim3(32), blk, 0, stream>>>(h1c, Wout, bout, (float*)d_out);
    }
}

// Round 16
// 4486.546 us; speedup vs baseline: 1.0139x; 1.0139x over previous
//
#include <hip/hip_runtime.h>
#include <hip/hip_bf16.h>

#define H1 1024
#define FOURH 4096
#define BATCH 512
#define SEQ 64
#define DIN 128
#define TDEC 8
#define SCR 68

typedef float f32x4 __attribute__((ext_vector_type(4)));
typedef __bf16 bf16x8 __attribute__((ext_vector_type(8)));

// global->LDS direct, 16B per lane. LDS dest is wave-uniform base + lane*16.
__device__ __forceinline__ void gl_lds16(const void* g, void* l) {
    __builtin_amdgcn_global_load_lds(
        (const __attribute__((address_space(1))) unsigned int*)g,
        (__attribute__((address_space(3))) unsigned int*)l, 16, 0, 0);
}

// ---------------------------------------------------------------------------
// Weights [4096][K] f32 -> permuted interleaved-pair bf16.
// dst row dr = uc*64 + c  (uc 0..63, c 0..63; unit = uc*16 + (c>>2), gate=c&3,
// src row r = gate*1024 + unit). Row layout: K/32 blocks of 128B =
// [hi(32 elems) 64B | lo(32 elems) 64B]  -> row bytes = 4K, same as f32 row.
// ---------------------------------------------------------------------------
__global__ __launch_bounds__(256) void conv_wpair_k(
    const float* __restrict__ src, __bf16* __restrict__ dst, int K, int ks5)
{
    int i = blockIdx.x * 256 + threadIdx.x;          // piece = 8 elems
    int c  = i & 63;
    int g  = (i >> 6) & 3;
    int t  = (i >> 8) & 1;
    int kk = (i >> 9) & ((1 << ks5) - 1);
    int uc = i >> (9 + ks5);
    int r  = (c & 3) * 1024 + uc * 16 + (c >> 2);
    const float* s = src + (size_t)r * K + kk * 32 + g * 8;
    bf16x8 p;
#pragma unroll
    for (int e = 0; e < 8; ++e) {
        float v = s[e];
        __bf16 h = (__bf16)v;
        p[e] = t ? (__bf16)(v - (float)h) : h;
    }
    int dr = uc * 64 + c;
    *(bf16x8*)(dst + (size_t)dr * 2 * K + kk * 64 + t * 32 + g * 8) = p;
}

// ---------------------------------------------------------------------------
// Fused GEMM + LSTM cell, deep-B-window variant.
// Block = 64 batch x 64 gate-cols (16 units). grid 512 = 8 bm x 64 uc
// (wg%8 = uc%8 -> B-sharing blocks on one XCD, SYNCHRONIZED for L2 dedup).
// 4 waves (2m x 2n), wave tile 32x32 (2x2 frags 16x16x32), 3-term hi/lo MFMA.
// LDS 80KB dynamic: A ring 4 x 8KB @0, B ring 6 x 8KB @32768 -> 2 blocks/CU.
// Interval (2 chunks): wait vmcnt(4) -> barrier -> issue A(p+2),A(p+3),
// B(p+4),B(p+5) -> compute p,p+1.  B flies ~2 intervals (2x in-flight
// uniques vs r14) with sharer dedup preserved (r15 showed rate ∝ in-flight
// uniques but stagger thrashed L2).
// Operand rows are interleaved-pair (128B per 32-k: hi64|lo64) — byte-
// compatible with f32 rows; layer-0's x segment stays f32 (a0f32, split
// in-register). Cell epilogue in-block; h out as interleaved pair.
// ---------------------------------------------------------------------------
__global__ __launch_bounds__(256, 2) void lstm_fb3(
    const char* __restrict__ a0, long long a0row_b, int k0, int a0f32,
    const char* __restrict__ a1,                     // h pair, row 4096B
    const __bf16* __restrict__ w0p,                  // permuted pair, row 4*k0 B
    const __bf16* __restrict__ w1p,                  // permuted pair, row 4096B
    const float* __restrict__ bias,
    float* __restrict__ cst, __bf16* __restrict__ hout)
{
    extern __shared__ char smem[];                   // 81920 B
    const int tid  = threadIdx.x;
    const int lane = tid & 63;
    const int w    = tid >> 6;                       // wave 0..3
    const int wm   = w >> 1, wn = w & 1;
    const int wg   = blockIdx.x;
    const int bm   = wg >> 6;                        // 0..7
    const int uc   = wg & 63;                        // 0..63

    const int nA = k0 >> 5;
    const int n  = nA + 32;                          // even for all layers

    // ---- staging geometry ----
    const int rsub = lane >> 3;
    const int slot = lane & 7;
    const int gsw  = slot ^ rsub;                    // XOR-swizzled src granule

    const char* paj0[2]; const char* paj1[2];
    const char* pbj0[2]; const char* pbj1[2];
#pragma unroll
    for (int j = 0; j < 2; ++j) {
        int ar = bm * 64 + w * 16 + j * 8 + rsub;
        paj0[j] = a0 + (size_t)ar * a0row_b + gsw * 16;
        paj1[j] = a1 + (size_t)ar * 4096 + gsw * 16;
        int c  = w * 16 + j * 8 + rsub;              // B row (gate-col)
        int dr = uc * 64 + c;
        pbj0[j] = (const char*)w0p + (size_t)dr * (4 * (size_t)k0) + gsw * 16;
        pbj1[j] = (const char*)w1p + (size_t)dr * 4096 + gsw * 16;
    }

    // LDS dests wave-uniform (HW adds lane*16); wave w sub-block j covers
    // rows w*16+j*8..+8 (1024B per gl_lds16).
    auto stageA = [&](int c) {                       // 2 gl_lds per wave
        char* buf = smem + (c & 3) * 8192;
        const char* const* pa = (c < nA) ? paj0 : paj1;
        size_t kb = (size_t)((c < nA) ? c : c - nA) * 128;
        gl_lds16(pa[0] + kb, buf + w * 2048);
        gl_lds16(pa[1] + kb, buf + w * 2048 + 1024);
    };
    auto stageB = [&](int c) {                       // 2 gl_lds per wave
        char* buf = smem + 32768 + (c % 6) * 8192;
        const char* const* pb = (c < nA) ? pbj0 : pbj1;
        size_t kb = (size_t)((c < nA) ? c : c - nA) * 128;
        gl_lds16(pb[0] + kb, buf + w * 2048);
        gl_lds16(pb[1] + kb, buf + w * 2048 + 1024);
    };

    // ---- fragment geometry ----
    int rA[2], rB[2];
#pragma unroll
    for (int f = 0; f < 2; ++f) {
        rA[f] = wm * 32 + f * 16 + (lane & 15);
        rB[f] = wn * 32 + f * 16 + (lane & 15);
    }
    const int s7 = lane & 7;
    const int g0 = lane >> 4;                        // k-granule group 0..3

    f32x4 acc[2][2];
#pragma unroll
    for (int a = 0; a < 2; ++a)
#pragma unroll
        for (int b = 0; b < 2; ++b)
            acc[a][b] = (f32x4){0.f, 0.f, 0.f, 0.f};

    auto chunk = [&](int c) {
        char* bufA = smem + (c & 3) * 8192;
        char* bufB = smem + 32768 + (c % 6) * 8192;
        bf16x8 ah[2], al[2], bh[2], bl[2];
        if (a0f32 && c < nA) {                       // layer-0 x chunks only
#pragma unroll
            for (int f = 0; f < 2; ++f) {
                f32x4 v0 = *(const f32x4*)(bufA + rA[f] * 128 + ((2 * g0    ) ^ s7) * 16);
                f32x4 v1 = *(const f32x4*)(bufA + rA[f] * 128 + ((2 * g0 + 1) ^ s7) * 16);
#pragma unroll
                for (int e = 0; e < 4; ++e) {
                    __bf16 h0 = (__bf16)v0[e];
                    ah[f][e] = h0; al[f][e] = (__bf16)(v0[e] - (float)h0);
                    __bf16 h1 = (__bf16)v1[e];
                    ah[f][e + 4] = h1; al[f][e + 4] = (__bf16)(v1[e] - (float)h1);
                }
            }
        } else {
#pragma unroll
            for (int f = 0; f < 2; ++f) {
                ah[f] = *(const bf16x8*)(bufA + rA[f] * 128 + ((g0    ) ^ s7) * 16);
                al[f] = *(const bf16x8*)(bufA + rA[f] * 128 + ((g0 + 4) ^ s7) * 16);
            }
        }
#pragma unroll
        for (int f = 0; f < 2; ++f) {
            bh[f] = *(const bf16x8*)(bufB + rB[f] * 128 + ((g0    ) ^ s7) * 16);
            bl[f] = *(const bf16x8*)(bufB + rB[f] * 128 + ((g0 + 4) ^ s7) * 16);
        }
#pragma unroll
        for (int mf = 0; mf < 2; ++mf)
#pragma unroll
            for (int nf = 0; nf < 2; ++nf) {
                acc[mf][nf] = __builtin_amdgcn_mfma_f32_16x16x32_bf16(
                    ah[mf], bh[nf], acc[mf][nf], 0, 0, 0);
                acc[mf][nf] = __builtin_amdgcn_mfma_f32_16x16x32_bf16(
                    ah[mf], bl[nf], acc[mf][nf], 0, 0, 0);
                acc[mf][nf] = __builtin_amdgcn_mfma_f32_16x16x32_bf16(
                    al[mf], bh[nf], acc[mf][nf], 0, 0, 0);
            }
    };

    // prologue mimics steady-state FIFO: [B0,B1][A0,A1][B2,B3]
    stageB(0); stageB(1);
    stageA(0); stageA(1);
    stageB(2); stageB(3);

    for (int p = 0; p < n; p += 2) {
        if (p + 2 < n) asm volatile("s_waitcnt vmcnt(4)" ::: "memory");
        else           asm volatile("s_waitcnt vmcnt(0)" ::: "memory");
        __builtin_amdgcn_sched_barrier(0);
        __builtin_amdgcn_s_barrier();
        __builtin_amdgcn_sched_barrier(0);

        if (p + 2 < n) { stageA(p + 2); stageA(p + 3); }
        if (p + 4 < n) { stageB(p + 4); stageB(p + 5); }

        chunk(p);
        chunk(p + 1);
        __builtin_amdgcn_sched_barrier(0);
    }

    // ---- epilogue: acc -> LDS scratch [64][SCR] f32 (A region) ----
    __syncthreads();
    float* scr = (float*)smem;
#pragma unroll
    for (int mf = 0; mf < 2; ++mf)
#pragma unroll
        for (int nf = 0; nf < 2; ++nf) {
            int row0 = wm * 32 + mf * 16 + (lane >> 4) * 4;   // m89 C layout
            int col  = wn * 32 + nf * 16 + (lane & 15);
#pragma unroll
            for (int j = 0; j < 4; ++j)
                scr[(row0 + j) * SCR + col] = acc[mf][nf][j];
        }
    __syncthreads();

    // ---- in-block cell: 64 rows x 16 units ----
#pragma unroll
    for (int p = 0; p < 4; ++p) {
        int item = p * 256 + tid;
        int u = item & 15;
        int r = item >> 4;                           // 0..63
        f32x4 g4 = *(const f32x4*)(scr + r * SCR + u * 4);
        int gu = uc * 16 + u;
        float gi = g4[0] + bias[gu];
        float gf = g4[1] + bias[H1 + gu];
        float gg = g4[2] + bias[2 * H1 + gu];
        float go = g4[3] + bias[3 * H1 + gu];
        float si = 1.f / (1.f + expf(-gi));
        float sf = 1.f / (1.f + expf(-gf));
        float so = 1.f / (1.f + expf(-go));
        int row_g = bm * 64 + r;
        size_t ci = (size_t)row_g * H1 + gu;
        float cc = sf * cst[ci] + si * tanhf(gg);
        cst[ci] = cc;
        float hv = so * tanhf(cc);
        __bf16 hh = (__bf16)hv;
        size_t hb = (size_t)row_g * 2048 + (gu >> 5) * 64 + (gu & 31);
        hout[hb]      = hh;
        hout[hb + 32] = (__bf16)(hv - (float)hh);
    }
}

// ---------------------------------------------------------------------------
// head on interleaved-pair h — wave-parallel: 16 lanes per output, shfl_xor
// reduce. grid 512 x 256 threads = 16 outputs/block.
// ---------------------------------------------------------------------------
__global__ __launch_bounds__(256) void head_pair2_k(
    const __bf16* __restrict__ hp, const float* __restrict__ W,
    const float* __restrict__ bo, float* __restrict__ out)
{
    int gid  = blockIdx.x * 16 + (threadIdx.x >> 4); // output 0..8191
    int l16  = threadIdx.x & 15;
    int b = gid >> 4, o = gid & 15;
    const __bf16* hr = hp + (size_t)b * 2048 + l16 * 128;  // 2 unit-blocks
    const float*  wr = W + (size_t)o * H1 + l16 * 64;
    float s = 0.f;
#pragma unroll
    for (int q = 0; q < 2; ++q) {
#pragma unroll
        for (int r = 0; r < 4; ++r) {
            bf16x8 vh = *(const bf16x8*)(hr + q * 64 + r * 8);
            bf16x8 vl = *(const bf16x8*)(hr + q * 64 + 32 + r * 8);
            const f32x4* wv = (const f32x4*)(wr + q * 32 + r * 8);
            f32x4 w0 = wv[0], w1 = wv[1];
#pragma unroll
            for (int e = 0; e < 4; ++e)
                s += ((float)vh[e] + (float)vl[e]) * w0[e];
#pragma unroll
            for (int e = 4; e < 8; ++e)
                s += ((float)vh[e] + (float)vl[e]) * w1[e - 4];
        }
    }
#pragma unroll
    for (int m = 8; m >= 1; m >>= 1)
        s += __shfl_xor(s, m, 16);
    if (l16 == 0) {
        float v = s + bo[o];
        out[(size_t)b * 32 + o]      = v;
        out[(size_t)b * 32 + 16 + o] = v;
    }
}

// ---------------------------------------------------------------------------
// FALLBACK (r9/r10-proven f32 all-LDS path) — runs only if ws too small.
// ---------------------------------------------------------------------------
__global__ __launch_bounds__(256, 1) void lstm_fused_f32(
    const float* __restrict__ a0v, long long arow_b, int k0,
    const float* __restrict__ w0v,
    const float* __restrict__ a1v,
    const float* __restrict__ w1v,
    const float* __restrict__ bias,
    float* __restrict__ cst, float* __restrict__ houtv)
{
    extern __shared__ char smem[];
    const int tid  = threadIdx.x;
    const int lane = tid & 63;
    const int w    = tid >> 6;
    const int wm   = w >> 1, wn = w & 1;
    const int wg   = blockIdx.x;
    const int bm   = wg >> 5;
    const int uc   = wg & 31;

    const int nA = k0 >> 5;
    const int n  = nA + 32;

    const int rsub = lane >> 3;
    const int slot = lane & 7;
    const int gsw  = slot ^ rsub;

    const char* paj0[2]; const char* paj1[2];
    const char* pbj0[4]; const char* pbj1[4];
#pragma unroll
    for (int j = 0; j < 2; ++j) {
        int ar = bm * 64 + w * 16 + j * 8 + rsub;
        paj0[j] = (const char*)a0v + (size_t)ar * arow_b + gsw * 16;
        paj1[j] = (const char*)a1v + (size_t)ar * 4096 + gsw * 16;
    }
#pragma unroll
    for (int j = 0; j < 4; ++j) {
        int c = w * 32 + j * 8 + rsub;
        int br0 = (c & 3) * H1 + uc * 32 + (c >> 2);
        pbj0[j] = (const char*)w0v + (size_t)br0 * (4 * (size_t)k0) + gsw * 16;
        pbj1[j] = (const char*)w1v + (size_t)br0 * 4096 + gsw * 16;
    }

    auto stage = [&](int ii, int buf) {
        char* bufA = smem + buf * 24576;
        char* bufB = bufA + 8192;
        size_t kb = (ii < nA) ? (size_t)ii * 128 : (size_t)(ii - nA) * 128;
        const char* const* pa = (ii < nA) ? paj0 : paj1;
        const char* const* pb = (ii < nA) ? pbj0 : pbj1;
#pragma unroll
        for (int j = 0; j < 2; ++j)
            gl_lds16(pa[j] + kb, bufA + (w * 2 + j) * 1024);
#pragma unroll
        for (int j = 0; j < 4; ++j)
            gl_lds16(pb[j] + kb, bufB + (w * 4 + j) * 1024);
    };

    int rAv[2], rBv[4];
#pragma unroll
    for (int f = 0; f < 2; ++f) rAv[f] = wm * 32 + f * 16 + (lane & 15);
#pragma unroll
    for (int f = 0; f < 4; ++f) rBv[f] = wn * 64 + f * 16 + (lane & 15);
    const int s7 = lane & 7;
    const int g0 = lane >> 4;

    f32x4 acc[2][4];
#pragma unroll
    for (int mf = 0; mf < 2; ++mf)
#pragma unroll
        for (int nf = 0; nf < 4; ++nf)
            acc[mf][nf] = (f32x4){0.f, 0.f, 0.f, 0.f};

    stage(0, 0); stage(1, 1); stage(2, 2); stage(3, 3); stage(4, 4);

    int buf = 0;
    for (int i = 0; i < n; ++i) {
        const int rem = n - i;
        if (rem >= 5)      asm volatile("s_waitcnt vmcnt(24)" ::: "memory");
        else if (rem == 4) asm volatile("s_waitcnt vmcnt(18)" ::: "memory");
        else if (rem == 3) asm volatile("s_waitcnt vmcnt(12)" ::: "memory");
        else if (rem == 2) asm volatile("s_waitcnt vmcnt(6)"  ::: "memory");
        else               asm volatile("s_waitcnt vmcnt(0)"  ::: "memory");
        __builtin_amdgcn_sched_barrier(0);
        __builtin_amdgcn_s_barrier();
        __builtin_amdgcn_sched_barrier(0);

        if (i + 5 < n) {
            int b5 = buf + 5; if (b5 >= 6) b5 -= 6;
            stage(i + 5, b5);
        }

        char* bufA = smem + buf * 24576;
        char* bufB = bufA + 8192;

        bf16x8 ah[2], al[2], bh[4], bl[4];
#pragma unroll
        for (int f = 0; f < 2; ++f) {
            f32x4 v0 = *(const f32x4*)(bufA + rAv[f] * 128 + ((2 * g0    ) ^ s7) * 16);
            f32x4 v1 = *(const f32x4*)(bufA + rAv[f] * 128 + ((2 * g0 + 1) ^ s7) * 16);
#pragma unroll
            for (int e = 0; e < 4; ++e) {
                __bf16 h0 = (__bf16)v0[e];
                ah[f][e] = h0; al[f][e] = (__bf16)(v0[e] - (float)h0);
                __bf16 h1 = (__bf16)v1[e];
                ah[f][e + 4] = h1; al[f][e + 4] = (__bf16)(v1[e] - (float)h1);
            }
        }
#pragma unroll
        for (int f = 0; f < 4; ++f) {
            f32x4 u0 = *(const f32x4*)(bufB + rBv[f] * 128 + ((2 * g0    ) ^ s7) * 16);
            f32x4 u1 = *(const f32x4*)(bufB + rBv[f] * 128 + ((2 * g0 + 1) ^ s7) * 16);
#pragma unroll
            for (int e = 0; e < 4; ++e) {
                __bf16 h0 = (__bf16)u0[e];
                bh[f][e] = h0; bl[f][e] = (__bf16)(u0[e] - (float)h0);
                __bf16 h1 = (__bf16)u1[e];
                bh[f][e + 4] = h1; bl[f][e + 4] = (__bf16)(u1[e] - (float)h1);
            }
        }
#pragma unroll
        for (int mf = 0; mf < 2; ++mf)
#pragma unroll
            for (int nf = 0; nf < 4; ++nf) {
                acc[mf][nf] = __builtin_amdgcn_mfma_f32_16x16x32_bf16(
                    ah[mf], bh[nf], acc[mf][nf], 0, 0, 0);
                acc[mf][nf] = __builtin_amdgcn_mfma_f32_16x16x32_bf16(
                    ah[mf], bl[nf], acc[mf][nf], 0, 0, 0);
                acc[mf][nf] = __builtin_amdgcn_mfma_f32_16x16x32_bf16(
                    al[mf], bh[nf], acc[mf][nf], 0, 0, 0);
            }
        __builtin_amdgcn_sched_barrier(0);
        buf = buf + 1; if (buf >= 6) buf -= 6;
    }

    __syncthreads();
    float* scr = (float*)smem;
#pragma unroll
    for (int mf = 0; mf < 2; ++mf)
#pragma unroll
        for (int nf = 0; nf < 4; ++nf) {
            int row0 = wm * 32 + mf * 16 + (lane >> 4) * 4;
            int col  = wn * 64 + nf * 16 + (lane & 15);
#pragma unroll
            for (int j = 0; j < 4; ++j)
                scr[(row0 + j) * 128 + col] = acc[mf][nf][j];
        }
    __syncthreads();

#pragma unroll
    for (int p = 0; p < 8; ++p) {
        int item = p * 256 + tid;
        int u = item & 31;
        int r = item >> 5;
        f32x4 g4 = *(const f32x4*)(scr + r * 128 + u * 4);
        int gu = uc * 32 + u;
        float gi = g4[0] + bias[gu];
        float gf = g4[1] + bias[H1 + gu];
        float gg = g4[2] + bias[2 * H1 + gu];
        float go = g4[3] + bias[3 * H1 + gu];
        float si = 1.f / (1.f + expf(-gi));
        float sf = 1.f / (1.f + expf(-gf));
        float so = 1.f / (1.f + expf(-go));
        size_t ci = (size_t)(bm * 64 + r) * H1 + gu;
        float cc = sf * cst[ci] + si * tanhf(gg);
        cst[ci] = cc;
        houtv[ci] = so * tanhf(cc);
    }
}

__global__ __launch_bounds__(256) void head_k(
    const float* __restrict__ h, const float* __restrict__ W,
    const float* __restrict__ bo, float* __restrict__ out)
{
    int idx = blockIdx.x * 256 + threadIdx.x;
    int b = idx >> 4, o = idx & 15;
    const f32x4* hv = (const f32x4*)(h + (size_t)b * H1);
    const f32x4* wv = (const f32x4*)(W + (size_t)o * H1);
    float s = bo[o];
#pragma unroll 4
    for (int k = 0; k < H1 / 4; ++k) {
        f32x4 a = hv[k];
        f32x4 wq = wv[k];
        s += a[0] * wq[0] + a[1] * wq[1] + a[2] * wq[2] + a[3] * wq[3];
    }
    out[(size_t)b * 32 + o]      = s;
    out[(size_t)b * 32 + 16 + o] = s;
}

// ===========================================================================
extern "C" void kernel_launch(void* const* d_in, const int* in_sizes, int n_in,
                              void* d_out, int out_size, void* d_ws, size_t ws_size,
                              hipStream_t stream)
{
    const float* x    = (const float*)d_in[0];
    const float* Wih0 = (const float*)d_in[1];
    const float* Whh0 = (const float*)d_in[2];
    const float* b0   = (const float*)d_in[3];
    const float* Wih1 = (const float*)d_in[4];
    const float* Whh1 = (const float*)d_in[5];
    const float* b1   = (const float*)d_in[6];
    const float* dWih = (const float*)d_in[7];
    const float* dWhh = (const float*)d_in[8];
    const float* db   = (const float*)d_in[9];
    const float* Wout = (const float*)d_in[10];
    const float* bout = (const float*)d_in[11];

    dim3 blk(256);
    const size_t WP_SMALL = (size_t)4096 * 128 * 4;    // 2MB   (K=128 pair)
    const size_t WP_BIG   = (size_t)4096 * 1024 * 4;   // 16MB  (K=1024 pair)
    const size_t HPB      = (size_t)BATCH * 4096;      // 2MB   h pair bytes
    const size_t CSZ      = (size_t)BATCH * H1;        // elems
    const size_t NEED1    = WP_SMALL + 7 * WP_BIG + 4 * HPB + 2 * CSZ * 4;
    const size_t SM3      = 81920;                     // lstm_fb3 dynamic LDS

    const float* dWih1 = dWih + (size_t)FOURH * H1;
    const float* dWhh1 = dWhh + (size_t)FOURH * H1;

    if (ws_size >= NEED1) {
        // ---------------- pair path ----------------
        char* wsb = (char*)d_ws;
        __bf16* Wih0p  = (__bf16*)wsb;
        __bf16* Whh0p  = (__bf16*)(wsb + WP_SMALL);
        __bf16* Wih1p  = (__bf16*)(wsb + WP_SMALL + WP_BIG);
        __bf16* Whh1p  = (__bf16*)(wsb + WP_SMALL + 2 * WP_BIG);
        __bf16* dWih0p = (__bf16*)(wsb + WP_SMALL + 3 * WP_BIG);
        __bf16* dWhh0p = (__bf16*)(wsb + WP_SMALL + 4 * WP_BIG);
        __bf16* dWih1p = (__bf16*)(wsb + WP_SMALL + 5 * WP_BIG);
        __bf16* dWhh1p = (__bf16*)(wsb + WP_SMALL + 6 * WP_BIG);
        char* sb = wsb + WP_SMALL + 7 * WP_BIG;
        __bf16* hp0a = (__bf16*)sb;
        __bf16* hp0b = (__bf16*)(sb + HPB);
        __bf16* hp1a = (__bf16*)(sb + 2 * HPB);
        __bf16* hp1b = (__bf16*)(sb + 3 * HPB);
        float*  c0   = (float*)(sb + 4 * HPB);
        float*  c1   = c0 + CSZ;

        auto convw = [&](const float* s, __bf16* d, int K, int ks5) {
            int total = 32768 * (K >> 5);
            conv_wpair_k<<<dim3(total / 256), blk, 0, stream>>>(s, d, K, ks5);
        };
        convw(Wih0, Wih0p, 128, 2);
        convw(Whh0, Whh0p, 1024, 5);
        convw(Wih1, Wih1p, 1024, 5);
        convw(Whh1, Whh1p, 1024, 5);
        convw(dWih,  dWih0p, 1024, 5);
        convw(dWih1, dWih1p, 1024, 5);
        convw(dWhh,  dWhh0p, 1024, 5);
        convw(dWhh1, dWhh1p, 1024, 5);

        hipMemsetAsync(sb, 0, 4 * HPB + 2 * CSZ * 4, stream);

        (void)hipFuncSetAttribute(reinterpret_cast<const void*>(&lstm_fb3),
                                  hipFuncAttributeMaxDynamicSharedMemorySize, SM3);

        dim3 fgrid(512);
        __bf16 *hc = hp0a, *hn = hp0b, *h1c = hp1a, *h1n = hp1b;
        const long long XROW = (long long)(SEQ * DIN * 4);
        for (int t = 0; t < SEQ; ++t) {
            lstm_fb3<<<fgrid, blk, SM3, stream>>>(
                (const char*)(x + (size_t)t * DIN), XROW, DIN, 1,
                (const char*)hc, Wih0p, Whh0p, b0, c0, hn);
            lstm_fb3<<<fgrid, blk, SM3, stream>>>(
                (const char*)hn, 4096LL, H1, 0,
                (const char*)h1c, Wih1p, Whh1p, b1, c1, h1n);
            __bf16* t0 = hc; hc = hn; hn = t0;
            __bf16* t1 = h1c; h1c = h1n; h1n = t1;
        }
        for (int s = 0; s < TDEC; ++s) {
            lstm_fb3<<<fgrid, blk, SM3, stream>>>(
                (const char*)h1c, 4096LL, H1, 0,
                (const char*)hc, dWih0p, dWhh0p, db, c0, hn);
            lstm_fb3<<<fgrid, blk, SM3, stream>>>(
                (const char*)hn, 4096LL, H1, 0,
                (const char*)h1c, dWih1p, dWhh1p, db + FOURH, c1, h1n);
            __bf16* t0 = hc; hc = hn; hn = t0;
            __bf16* t1 = h1c; h1c = h1n; h1n = t1;
        }
        head_pair2_k<<<dim3(512), blk, 0, stream>>>(h1c, Wout, bout, (float*)d_out);
    } else {
        // ---------------- f32 fallback (proven) ----------------
        float* h0a = (float*)d_ws;
        float* h0b = h0a + CSZ;
        float* h1a = h0b + CSZ;
        float* h1b = h1a + CSZ;
        float* c0  = h1b + CSZ;
        float* c1  = c0 + CSZ;
        hipMemsetAsync(h0a, 0, 6 * CSZ * 4, stream);

        (void)hipFuncSetAttribute(reinterpret_cast<const void*>(&lstm_fused_f32),
                                  hipFuncAttributeMaxDynamicSharedMemorySize, 147456);

        dim3 oldgrid(256);
        float *hc = h0a, *hn = h0b, *h1c = h1a, *h1n = h1b;
        for (int t = 0; t < SEQ; ++t) {
            lstm_fused_f32<<<oldgrid, blk, 147456, stream>>>(
                x + (size_t)t * DIN, (long long)(SEQ * DIN * 4), DIN, Wih0,
                hc, Whh0, b0, c0, hn);
            lstm_fused_f32<<<oldgrid, blk, 147456, stream>>>(
                hn, 4096LL, H1, Wih1, h1c, Whh1, b1, c1, h1n);
            float* t0 = hc; hc = hn; hn = t0;
            float* t1 = h1c; h1c = h1n; h1n = t1;
        }
        for (int s = 0; s < TDEC; ++s) {
            lstm_fused_f32<<<oldgrid, blk, 147456, stream>>>(
                h1c, 4096LL, H1, dWih, hc, dWhh, db, c0, hn);
            lstm_fused_f32<<<oldgrid, blk, 147456, stream>>>(
                hn, 4096LL, H1, dWih1, h1c, dWhh1, db + FOURH, c1, h1n);
            float* t0 = hc; hc = hn; hn = t0;
            float* t1 = h1c; h1c = h1n; h1n = t1;
        }
        head_k<<<dim3(32), blk, 0, stream>>>(h1c, Wout, bout, (float*)d_out);
    }
}

// Round 17
// 4366.397 us; speedup vs baseline: 1.0418x; 1.0275x over previous
//
#include <hip/hip_runtime.h>
#include <hip/hip_bf16.h>

#define H1 1024
#define FOURH 4096
#define BATCH 512
#define SEQ 64
#define DIN 128
#define TDEC 8
#define SCR 68

typedef float f32x4 __attribute__((ext_vector_type(4)));
typedef __bf16 bf16x8 __attribute__((ext_vector_type(8)));

// global->LDS direct, 16B per lane. LDS dest is wave-uniform base + lane*16.
__device__ __forceinline__ void gl_lds16(const void* g, void* l) {
    __builtin_amdgcn_global_load_lds(
        (const __attribute__((address_space(1))) unsigned int*)g,
        (__attribute__((address_space(3))) unsigned int*)l, 16, 0, 0);
}

// ---------------------------------------------------------------------------
// Weights [4096][K] f32 -> permuted interleaved-pair bf16.
// dst row dr = uc*64 + c  (uc 0..63, c 0..63; unit = uc*16 + (c>>2), gate=c&3,
// src row r = gate*1024 + unit). Row layout: K/32 blocks of 128B =
// [hi(32 elems) 64B | lo(32 elems) 64B]  -> row bytes = 4K, same as f32 row.
// ---------------------------------------------------------------------------
__global__ __launch_bounds__(256) void conv_wpair_k(
    const float* __restrict__ src, __bf16* __restrict__ dst, int K, int ks5)
{
    int i = blockIdx.x * 256 + threadIdx.x;          // piece = 8 elems
    int c  = i & 63;
    int g  = (i >> 6) & 3;
    int t  = (i >> 8) & 1;
    int kk = (i >> 9) & ((1 << ks5) - 1);
    int uc = i >> (9 + ks5);
    int r  = (c & 3) * 1024 + uc * 16 + (c >> 2);
    const float* s = src + (size_t)r * K + kk * 32 + g * 8;
    bf16x8 p;
#pragma unroll
    for (int e = 0; e < 8; ++e) {
        float v = s[e];
        __bf16 h = (__bf16)v;
        p[e] = t ? (__bf16)(v - (float)h) : h;
    }
    int dr = uc * 64 + c;
    *(bf16x8*)(dst + (size_t)dr * 2 * K + kk * 64 + t * 32 + g * 8) = p;
}

// ---------------------------------------------------------------------------
// Fused GEMM + LSTM cell, 2-FRONT stagger variant.
// Block = 64 batch x 64 gate-cols (16 units). grid 512 = 8 bm x 64 uc
// (wg%8 = uc%8 -> B-sharing blocks on one XCD). 4 waves (2m x 2n), wave tile
// 32x32 (2x2 frags 16x16x32), 3-term hi/lo MFMA. 2 blocks/CU (64KB LDS).
// Barrier every TWO chunks (proven r13/r14 schedule, vmcnt(0)).
// STAGGER: bm 0-3 walk chunks from 0, bm 4-7 from n/2 (wrapped) -> TWO unique
// request streams per B panel (r15/r16 evidence: fetch rate scales with
// stream count, ~125 GB/s/XCD/stream), reuse distance = half panel ~2MB/XCD
// < 4MB L2 so dedup within each front group of 4 is preserved.
// Operand rows are interleaved-pair (128B per 32-k: hi64|lo64) — byte-
// compatible with f32 rows; layer-0's x segment stays f32 (a0f32, split
// in-register, physical idx < nA). Cell epilogue in-block; h out as pair.
// ---------------------------------------------------------------------------
__global__ __launch_bounds__(256, 2) void lstm_fb4(
    const char* __restrict__ a0, long long a0row_b, int k0, int a0f32,
    const char* __restrict__ a1,                     // h pair, row 4096B
    const __bf16* __restrict__ w0p,                  // permuted pair, row 4*k0 B
    const __bf16* __restrict__ w1p,                  // permuted pair, row 4096B
    const float* __restrict__ bias,
    float* __restrict__ cst, __bf16* __restrict__ hout)
{
    __shared__ char smem[65536];                     // 4 bufs x (A 8KB + B 8KB)
    const int tid  = threadIdx.x;
    const int lane = tid & 63;
    const int w    = tid >> 6;                       // wave 0..3
    const int wm   = w >> 1, wn = w & 1;
    const int wg   = blockIdx.x;
    const int bm   = wg >> 6;                        // 0..7
    const int uc   = wg & 63;                        // 0..63

    const int nA = k0 >> 5;
    const int n  = nA + 32;                          // even (36 or 64)
    const int off = (bm & 4) ? (n >> 1) : 0;         // 2 fronts; n/2 even

    // ---- staging geometry: 4 gl_lds16 per wave per chunk (A 2 + B 2) ----
    const int rsub = lane >> 3;
    const int slot = lane & 7;
    const int gsw  = slot ^ rsub;                    // XOR-swizzled src granule

    const char* paj0[2]; const char* paj1[2];
    const char* pbj0[2]; const char* pbj1[2];
#pragma unroll
    for (int j = 0; j < 2; ++j) {
        int ar = bm * 64 + w * 16 + j * 8 + rsub;
        paj0[j] = a0 + (size_t)ar * a0row_b + gsw * 16;
        paj1[j] = a1 + (size_t)ar * 4096 + gsw * 16;
        int c  = w * 16 + j * 8 + rsub;              // B row (gate-col)
        int dr = uc * 64 + c;
        pbj0[j] = (const char*)w0p + (size_t)dr * (4 * (size_t)k0) + gsw * 16;
        pbj1[j] = (const char*)w1p + (size_t)dr * 4096 + gsw * 16;
    }

    // LDS dests wave-uniform (HW adds lane*16); wave w sub-block j covers
    // rows w*16+j*8..+8 (1024B per gl_lds16).
    auto stage = [&](int phys, int buf) {
        char* bufA = smem + buf * 16384;
        char* bufB = bufA + 8192;
        if (phys < nA) {
            size_t kb = (size_t)phys * 128;
#pragma unroll
            for (int j = 0; j < 2; ++j) {
                gl_lds16(paj0[j] + kb, bufA + w * 2048 + j * 1024);
                gl_lds16(pbj0[j] + kb, bufB + w * 2048 + j * 1024);
            }
        } else {
            size_t kb = (size_t)(phys - nA) * 128;
#pragma unroll
            for (int j = 0; j < 2; ++j) {
                gl_lds16(paj1[j] + kb, bufA + w * 2048 + j * 1024);
                gl_lds16(pbj1[j] + kb, bufB + w * 2048 + j * 1024);
            }
        }
    };

    // ---- fragment geometry ----
    int rA[2], rB[2];
#pragma unroll
    for (int f = 0; f < 2; ++f) {
        rA[f] = wm * 32 + f * 16 + (lane & 15);
        rB[f] = wn * 32 + f * 16 + (lane & 15);
    }
    const int s7 = lane & 7;
    const int g0 = lane >> 4;                        // k-granule group 0..3

    f32x4 acc[2][2];
#pragma unroll
    for (int a = 0; a < 2; ++a)
#pragma unroll
        for (int b = 0; b < 2; ++b)
            acc[a][b] = (f32x4){0.f, 0.f, 0.f, 0.f};

    auto chunk = [&](int phys, int buf) {
        char* bufA = smem + buf * 16384;
        char* bufB = bufA + 8192;
        bf16x8 ah[2], al[2], bh[2], bl[2];
        if (a0f32 && phys < nA) {                    // layer-0 x chunks only
#pragma unroll
            for (int f = 0; f < 2; ++f) {
                f32x4 v0 = *(const f32x4*)(bufA + rA[f] * 128 + ((2 * g0    ) ^ s7) * 16);
                f32x4 v1 = *(const f32x4*)(bufA + rA[f] * 128 + ((2 * g0 + 1) ^ s7) * 16);
#pragma unroll
                for (int e = 0; e < 4; ++e) {
                    __bf16 h0 = (__bf16)v0[e];
                    ah[f][e] = h0; al[f][e] = (__bf16)(v0[e] - (float)h0);
                    __bf16 h1 = (__bf16)v1[e];
                    ah[f][e + 4] = h1; al[f][e + 4] = (__bf16)(v1[e] - (float)h1);
                }
            }
        } else {
#pragma unroll
            for (int f = 0; f < 2; ++f) {
                ah[f] = *(const bf16x8*)(bufA + rA[f] * 128 + ((g0    ) ^ s7) * 16);
                al[f] = *(const bf16x8*)(bufA + rA[f] * 128 + ((g0 + 4) ^ s7) * 16);
            }
        }
#pragma unroll
        for (int f = 0; f < 2; ++f) {
            bh[f] = *(const bf16x8*)(bufB + rB[f] * 128 + ((g0    ) ^ s7) * 16);
            bl[f] = *(const bf16x8*)(bufB + rB[f] * 128 + ((g0 + 4) ^ s7) * 16);
        }
#pragma unroll
        for (int mf = 0; mf < 2; ++mf)
#pragma unroll
            for (int nf = 0; nf < 2; ++nf) {
                acc[mf][nf] = __builtin_amdgcn_mfma_f32_16x16x32_bf16(
                    ah[mf], bh[nf], acc[mf][nf], 0, 0, 0);
                acc[mf][nf] = __builtin_amdgcn_mfma_f32_16x16x32_bf16(
                    ah[mf], bl[nf], acc[mf][nf], 0, 0, 0);
                acc[mf][nf] = __builtin_amdgcn_mfma_f32_16x16x32_bf16(
                    al[mf], bh[nf], acc[mf][nf], 0, 0, 0);
            }
    };

    // prologue: first interval's chunks (physical = off, off+1)
    stage(off,     0);
    stage(off + 1, 1);

    for (int p = 0; p < n; p += 2) {
        asm volatile("s_waitcnt vmcnt(0)" ::: "memory");
        __builtin_amdgcn_sched_barrier(0);
        __builtin_amdgcn_s_barrier();
        __builtin_amdgcn_sched_barrier(0);

        if (p + 2 < n) {                             // bufs freed last interval
            int q = p + 2 + off; if (q >= n) q -= n; // q even -> q+1 in range
            stage(q,     (p + 2) & 3);
            stage(q + 1, (p + 3) & 3);
        }

        int c0 = p + off; if (c0 >= n) c0 -= n;      // c0 even
        chunk(c0,     p & 3);
        chunk(c0 + 1, (p + 1) & 3);
        __builtin_amdgcn_sched_barrier(0);
    }

    // ---- epilogue: acc -> LDS scratch [64][SCR] f32 ----
    __syncthreads();
    float* scr = (float*)smem;
#pragma unroll
    for (int mf = 0; mf < 2; ++mf)
#pragma unroll
        for (int nf = 0; nf < 2; ++nf) {
            int row0 = wm * 32 + mf * 16 + (lane >> 4) * 4;   // m89 C layout
            int col  = wn * 32 + nf * 16 + (lane & 15);
#pragma unroll
            for (int j = 0; j < 4; ++j)
                scr[(row0 + j) * SCR + col] = acc[mf][nf][j];
        }
    __syncthreads();

    // ---- in-block cell: 64 rows x 16 units ----
#pragma unroll
    for (int p = 0; p < 4; ++p) {
        int item = p * 256 + tid;
        int u = item & 15;
        int r = item >> 4;                           // 0..63
        f32x4 g4 = *(const f32x4*)(scr + r * SCR + u * 4);
        int gu = uc * 16 + u;
        float gi = g4[0] + bias[gu];
        float gf = g4[1] + bias[H1 + gu];
        float gg = g4[2] + bias[2 * H1 + gu];
        float go = g4[3] + bias[3 * H1 + gu];
        float si = 1.f / (1.f + expf(-gi));
        float sf = 1.f / (1.f + expf(-gf));
        float so = 1.f / (1.f + expf(-go));
        int row_g = bm * 64 + r;
        size_t ci = (size_t)row_g * H1 + gu;
        float cc = sf * cst[ci] + si * tanhf(gg);
        cst[ci] = cc;
        float hv = so * tanhf(cc);
        __bf16 hh = (__bf16)hv;
        size_t hb = (size_t)row_g * 2048 + (gu >> 5) * 64 + (gu & 31);
        hout[hb]      = hh;
        hout[hb + 32] = (__bf16)(hv - (float)hh);
    }
}

// ---------------------------------------------------------------------------
// head on interleaved-pair h — wave-parallel: 16 lanes per output, shfl_xor
// reduce. grid 512 x 256 threads = 16 outputs/block.
// ---------------------------------------------------------------------------
__global__ __launch_bounds__(256) void head_pair2_k(
    const __bf16* __restrict__ hp, const float* __restrict__ W,
    const float* __restrict__ bo, float* __restrict__ out)
{
    int gid  = blockIdx.x * 16 + (threadIdx.x >> 4); // output 0..8191
    int l16  = threadIdx.x & 15;
    int b = gid >> 4, o = gid & 15;
    const __bf16* hr = hp + (size_t)b * 2048 + l16 * 128;  // 2 unit-blocks
    const float*  wr = W + (size_t)o * H1 + l16 * 64;
    float s = 0.f;
#pragma unroll
    for (int q = 0; q < 2; ++q) {
#pragma unroll
        for (int r = 0; r < 4; ++r) {
            bf16x8 vh = *(const bf16x8*)(hr + q * 64 + r * 8);
            bf16x8 vl = *(const bf16x8*)(hr + q * 64 + 32 + r * 8);
            const f32x4* wv = (const f32x4*)(wr + q * 32 + r * 8);
            f32x4 w0 = wv[0], w1 = wv[1];
#pragma unroll
            for (int e = 0; e < 4; ++e)
                s += ((float)vh[e] + (float)vl[e]) * w0[e];
#pragma unroll
            for (int e = 4; e < 8; ++e)
                s += ((float)vh[e] + (float)vl[e]) * w1[e - 4];
        }
    }
#pragma unroll
    for (int m = 8; m >= 1; m >>= 1)
        s += __shfl_xor(s, m, 16);
    if (l16 == 0) {
        float v = s + bo[o];
        out[(size_t)b * 32 + o]      = v;
        out[(size_t)b * 32 + 16 + o] = v;
    }
}

// ---------------------------------------------------------------------------
// FALLBACK (r9/r10-proven f32 all-LDS path) — runs only if ws too small.
// ---------------------------------------------------------------------------
__global__ __launch_bounds__(256, 1) void lstm_fused_f32(
    const float* __restrict__ a0v, long long arow_b, int k0,
    const float* __restrict__ w0v,
    const float* __restrict__ a1v,
    const float* __restrict__ w1v,
    const float* __restrict__ bias,
    float* __restrict__ cst, float* __restrict__ houtv)
{
    extern __shared__ char smem[];
    const int tid  = threadIdx.x;
    const int lane = tid & 63;
    const int w    = tid >> 6;
    const int wm   = w >> 1, wn = w & 1;
    const int wg   = blockIdx.x;
    const int bm   = wg >> 5;
    const int uc   = wg & 31;

    const int nA = k0 >> 5;
    const int n  = nA + 32;

    const int rsub = lane >> 3;
    const int slot = lane & 7;
    const int gsw  = slot ^ rsub;

    const char* paj0[2]; const char* paj1[2];
    const char* pbj0[4]; const char* pbj1[4];
#pragma unroll
    for (int j = 0; j < 2; ++j) {
        int ar = bm * 64 + w * 16 + j * 8 + rsub;
        paj0[j] = (const char*)a0v + (size_t)ar * arow_b + gsw * 16;
        paj1[j] = (const char*)a1v + (size_t)ar * 4096 + gsw * 16;
    }
#pragma unroll
    for (int j = 0; j < 4; ++j) {
        int c = w * 32 + j * 8 + rsub;
        int br0 = (c & 3) * H1 + uc * 32 + (c >> 2);
        pbj0[j] = (const char*)w0v + (size_t)br0 * (4 * (size_t)k0) + gsw * 16;
        pbj1[j] = (const char*)w1v + (size_t)br0 * 4096 + gsw * 16;
    }

    auto stage = [&](int ii, int buf) {
        char* bufA = smem + buf * 24576;
        char* bufB = bufA + 8192;
        size_t kb = (ii < nA) ? (size_t)ii * 128 : (size_t)(ii - nA) * 128;
        const char* const* pa = (ii < nA) ? paj0 : paj1;
        const char* const* pb = (ii < nA) ? pbj0 : pbj1;
#pragma unroll
        for (int j = 0; j < 2; ++j)
            gl_lds16(pa[j] + kb, bufA + (w * 2 + j) * 1024);
#pragma unroll
        for (int j = 0; j < 4; ++j)
            gl_lds16(pb[j] + kb, bufB + (w * 4 + j) * 1024);
    };

    int rAv[2], rBv[4];
#pragma unroll
    for (int f = 0; f < 2; ++f) rAv[f] = wm * 32 + f * 16 + (lane & 15);
#pragma unroll
    for (int f = 0; f < 4; ++f) rBv[f] = wn * 64 + f * 16 + (lane & 15);
    const int s7 = lane & 7;
    const int g0 = lane >> 4;

    f32x4 acc[2][4];
#pragma unroll
    for (int mf = 0; mf < 2; ++mf)
#pragma unroll
        for (int nf = 0; nf < 4; ++nf)
            acc[mf][nf] = (f32x4){0.f, 0.f, 0.f, 0.f};

    stage(0, 0); stage(1, 1); stage(2, 2); stage(3, 3); stage(4, 4);

    int buf = 0;
    for (int i = 0; i < n; ++i) {
        const int rem = n - i;
        if (rem >= 5)      asm volatile("s_waitcnt vmcnt(24)" ::: "memory");
        else if (rem == 4) asm volatile("s_waitcnt vmcnt(18)" ::: "memory");
        else if (rem == 3) asm volatile("s_waitcnt vmcnt(12)" ::: "memory");
        else if (rem == 2) asm volatile("s_waitcnt vmcnt(6)"  ::: "memory");
        else               asm volatile("s_waitcnt vmcnt(0)"  ::: "memory");
        __builtin_amdgcn_sched_barrier(0);
        __builtin_amdgcn_s_barrier();
        __builtin_amdgcn_sched_barrier(0);

        if (i + 5 < n) {
            int b5 = buf + 5; if (b5 >= 6) b5 -= 6;
            stage(i + 5, b5);
        }

        char* bufA = smem + buf * 24576;
        char* bufB = bufA + 8192;

        bf16x8 ah[2], al[2], bh[4], bl[4];
#pragma unroll
        for (int f = 0; f < 2; ++f) {
            f32x4 v0 = *(const f32x4*)(bufA + rAv[f] * 128 + ((2 * g0    ) ^ s7) * 16);
            f32x4 v1 = *(const f32x4*)(bufA + rAv[f] * 128 + ((2 * g0 + 1) ^ s7) * 16);
#pragma unroll
            for (int e = 0; e < 4; ++e) {
                __bf16 h0 = (__bf16)v0[e];
                ah[f][e] = h0; al[f][e] = (__bf16)(v0[e] - (float)h0);
                __bf16 h1 = (__bf16)v1[e];
                ah[f][e + 4] = h1; al[f][e + 4] = (__bf16)(v1[e] - (float)h1);
            }
        }
#pragma unroll
        for (int f = 0; f < 4; ++f) {
            f32x4 u0 = *(const f32x4*)(bufB + rBv[f] * 128 + ((2 * g0    ) ^ s7) * 16);
            f32x4 u1 = *(const f32x4*)(bufB + rBv[f] * 128 + ((2 * g0 + 1) ^ s7) * 16);
#pragma unroll
            for (int e = 0; e < 4; ++e) {
                __bf16 h0 = (__bf16)u0[e];
                bh[f][e] = h0; bl[f][e] = (__bf16)(u0[e] - (float)h0);
                __bf16 h1 = (__bf16)u1[e];
                bh[f][e + 4] = h1; bl[f][e + 4] = (__bf16)(u1[e] - (float)h1);
            }
        }
#pragma unroll
        for (int mf = 0; mf < 2; ++mf)
#pragma unroll
            for (int nf = 0; nf < 4; ++nf) {
                acc[mf][nf] = __builtin_amdgcn_mfma_f32_16x16x32_bf16(
                    ah[mf], bh[nf], acc[mf][nf], 0, 0, 0);
                acc[mf][nf] = __builtin_amdgcn_mfma_f32_16x16x32_bf16(
                    ah[mf], bl[nf], acc[mf][nf], 0, 0, 0);
                acc[mf][nf] = __builtin_amdgcn_mfma_f32_16x16x32_bf16(
                    al[mf], bh[nf], acc[mf][nf], 0, 0, 0);
            }
        __builtin_amdgcn_sched_barrier(0);
        buf = buf + 1; if (buf >= 6) buf -= 6;
    }

    __syncthreads();
    float* scr = (float*)smem;
#pragma unroll
    for (int mf = 0; mf < 2; ++mf)
#pragma unroll
        for (int nf = 0; nf < 4; ++nf) {
            int row0 = wm * 32 + mf * 16 + (lane >> 4) * 4;
            int col  = wn * 64 + nf * 16 + (lane & 15);
#pragma unroll
            for (int j = 0; j < 4; ++j)
                scr[(row0 + j) * 128 + col] = acc[mf][nf][j];
        }
    __syncthreads();

#pragma unroll
    for (int p = 0; p < 8; ++p) {
        int item = p * 256 + tid;
        int u = item & 31;
        int r = item >> 5;
        f32x4 g4 = *(const f32x4*)(scr + r * 128 + u * 4);
        int gu = uc * 32 + u;
        float gi = g4[0] + bias[gu];
        float gf = g4[1] + bias[H1 + gu];
        float gg = g4[2] + bias[2 * H1 + gu];
        float go = g4[3] + bias[3 * H1 + gu];
        float si = 1.f / (1.f + expf(-gi));
        float sf = 1.f / (1.f + expf(-gf));
        float so = 1.f / (1.f + expf(-go));
        size_t ci = (size_t)(bm * 64 + r) * H1 + gu;
        float cc = sf * cst[ci] + si * tanhf(gg);
        cst[ci] = cc;
        houtv[ci] = so * tanhf(cc);
    }
}

__global__ __launch_bounds__(256) void head_k(
    const float* __restrict__ h, const float* __restrict__ W,
    const float* __restrict__ bo, float* __restrict__ out)
{
    int idx = blockIdx.x * 256 + threadIdx.x;
    int b = idx >> 4, o = idx & 15;
    const f32x4* hv = (const f32x4*)(h + (size_t)b * H1);
    const f32x4* wv = (const f32x4*)(W + (size_t)o * H1);
    float s = bo[o];
#pragma unroll 4
    for (int k = 0; k < H1 / 4; ++k) {
        f32x4 a = hv[k];
        f32x4 wq = wv[k];
        s += a[0] * wq[0] + a[1] * wq[1] + a[2] * wq[2] + a[3] * wq[3];
    }
    out[(size_t)b * 32 + o]      = s;
    out[(size_t)b * 32 + 16 + o] = s;
}

// ===========================================================================
extern "C" void kernel_launch(void* const* d_in, const int* in_sizes, int n_in,
                              void* d_out, int out_size, void* d_ws, size_t ws_size,
                              hipStream_t stream)
{
    const float* x    = (const float*)d_in[0];
    const float* Wih0 = (const float*)d_in[1];
    const float* Whh0 = (const float*)d_in[2];
    const float* b0   = (const float*)d_in[3];
    const float* Wih1 = (const float*)d_in[4];
    const float* Whh1 = (const float*)d_in[5];
    const float* b1   = (const float*)d_in[6];
    const float* dWih = (const float*)d_in[7];
    const float* dWhh = (const float*)d_in[8];
    const float* db   = (const float*)d_in[9];
    const float* Wout = (const float*)d_in[10];
    const float* bout = (const float*)d_in[11];

    dim3 blk(256);
    const size_t WP_SMALL = (size_t)4096 * 128 * 4;    // 2MB   (K=128 pair)
    const size_t WP_BIG   = (size_t)4096 * 1024 * 4;   // 16MB  (K=1024 pair)
    const size_t HPB      = (size_t)BATCH * 4096;      // 2MB   h pair bytes
    const size_t CSZ      = (size_t)BATCH * H1;        // elems
    const size_t NEED1    = WP_SMALL + 7 * WP_BIG + 4 * HPB + 2 * CSZ * 4;

    const float* dWih1 = dWih + (size_t)FOURH * H1;
    const float* dWhh1 = dWhh + (size_t)FOURH * H1;

    if (ws_size >= NEED1) {
        // ---------------- pair path ----------------
        char* wsb = (char*)d_ws;
        __bf16* Wih0p  = (__bf16*)wsb;
        __bf16* Whh0p  = (__bf16*)(wsb + WP_SMALL);
        __bf16* Wih1p  = (__bf16*)(wsb + WP_SMALL + WP_BIG);
        __bf16* Whh1p  = (__bf16*)(wsb + WP_SMALL + 2 * WP_BIG);
        __bf16* dWih0p = (__bf16*)(wsb + WP_SMALL + 3 * WP_BIG);
        __bf16* dWhh0p = (__bf16*)(wsb + WP_SMALL + 4 * WP_BIG);
        __bf16* dWih1p = (__bf16*)(wsb + WP_SMALL + 5 * WP_BIG);
        __bf16* dWhh1p = (__bf16*)(wsb + WP_SMALL + 6 * WP_BIG);
        char* sb = wsb + WP_SMALL + 7 * WP_BIG;
        __bf16* hp0a = (__bf16*)sb;
        __bf16* hp0b = (__bf16*)(sb + HPB);
        __bf16* hp1a = (__bf16*)(sb + 2 * HPB);
        __bf16* hp1b = (__bf16*)(sb + 3 * HPB);
        float*  c0   = (float*)(sb + 4 * HPB);
        float*  c1   = c0 + CSZ;

        auto convw = [&](const float* s, __bf16* d, int K, int ks5) {
            int total = 32768 * (K >> 5);
            conv_wpair_k<<<dim3(total / 256), blk, 0, stream>>>(s, d, K, ks5);
        };
        convw(Wih0, Wih0p, 128, 2);
        convw(Whh0, Whh0p, 1024, 5);
        convw(Wih1, Wih1p, 1024, 5);
        convw(Whh1, Whh1p, 1024, 5);
        convw(dWih,  dWih0p, 1024, 5);
        convw(dWih1, dWih1p, 1024, 5);
        convw(dWhh,  dWhh0p, 1024, 5);
        convw(dWhh1, dWhh1p, 1024, 5);

        hipMemsetAsync(sb, 0, 4 * HPB + 2 * CSZ * 4, stream);

        dim3 fgrid(512);
        __bf16 *hc = hp0a, *hn = hp0b, *h1c = hp1a, *h1n = hp1b;
        const long long XROW = (long long)(SEQ * DIN * 4);
        for (int t = 0; t < SEQ; ++t) {
            lstm_fb4<<<fgrid, blk, 0, stream>>>(
                (const char*)(x + (size_t)t * DIN), XROW, DIN, 1,
                (const char*)hc, Wih0p, Whh0p, b0, c0, hn);
            lstm_fb4<<<fgrid, blk, 0, stream>>>(
                (const char*)hn, 4096LL, H1, 0,
                (const char*)h1c, Wih1p, Whh1p, b1, c1, h1n);
            __bf16* t0 = hc; hc = hn; hn = t0;
            __bf16* t1 = h1c; h1c = h1n; h1n = t1;
        }
        for (int s = 0; s < TDEC; ++s) {
            lstm_fb4<<<fgrid, blk, 0, stream>>>(
                (const char*)h1c, 4096LL, H1, 0,
                (const char*)hc, dWih0p, dWhh0p, db, c0, hn);
            lstm_fb4<<<fgrid, blk, 0, stream>>>(
                (const char*)hn, 4096LL, H1, 0,
                (const char*)h1c, dWih1p, dWhh1p, db + FOURH, c1, h1n);
            __bf16* t0 = hc; hc = hn; hn = t0;
            __bf16* t1 = h1c; h1c = h1n; h1n = t1;
        }
        head_pair2_k<<<dim3(512), blk, 0, stream>>>(h1c, Wout, bout, (float*)d_out);
    } else {
        // ---------------- f32 fallback (proven) ----------------
        float* h0a = (float*)d_ws;
        float* h0b = h0a + CSZ;
        float* h1a = h0b + CSZ;
        float* h1b = h1a + CSZ;
        float* c0  = h1b + CSZ;
        float* c1  = c0 + CSZ;
        hipMemsetAsync(h0a, 0, 6 * CSZ * 4, stream);

        (void)hipFuncSetAttribute(reinterpret_cast<const void*>(&lstm_fused_f32),
                                  hipFuncAttributeMaxDynamicSharedMemorySize, 147456);

        dim3 oldgrid(256);
        float *hc = h0a, *hn = h0b, *h1c = h1a, *h1n = h1b;
        for (int t = 0; t < SEQ; ++t) {
            lstm_fused_f32<<<oldgrid, blk, 147456, stream>>>(
                x + (size_t)t * DIN, (long long)(SEQ * DIN * 4), DIN, Wih0,
                hc, Whh0, b0, c0, hn);
            lstm_fused_f32<<<oldgrid, blk, 147456, stream>>>(
                hn, 4096LL, H1, Wih1, h1c, Whh1, b1, c1, h1n);
            float* t0 = hc; hc = hn; hn = t0;
            float* t1 = h1c; h1c = h1n; h1n = t1;
        }
        for (int s = 0; s < TDEC; ++s) {
            lstm_fused_f32<<<oldgrid, blk, 147456, stream>>>(
                h1c, 4096LL, H1, dWih, hc, dWhh, db, c0, hn);
            lstm_fused_f32<<<oldgrid, blk, 147456, stream>>>(
                hn, 4096LL, H1, dWih1, h1c, dWhh1, db + FOURH, c1, h1n);
            float* t0 = hc; hc = hn; hn = t0;
            float* t1 = h1c; h1c = h1n; h1n = t1;
        }
        head_k<<<dim3(32), blk, 0, stream>>>(h1c, Wout, bout, (float*)d_out);
    }
}

// Round 18
// 3291.615 us; speedup vs baseline: 1.3820x; 1.3265x over previous
//
#include <hip/hip_runtime.h>
#include <hip/hip_bf16.h>

#define H1 1024
#define FOURH 4096
#define BATCH 512
#define SEQ 64
#define DIN 128
#define TDEC 8
#define SCR 68

typedef float f32x4 __attribute__((ext_vector_type(4)));
typedef _Float16 f16x8 __attribute__((ext_vector_type(8)));
typedef __bf16 bf16x8 __attribute__((ext_vector_type(8)));

// global->LDS direct, 16B per lane. LDS dest is wave-uniform base + lane*16.
__device__ __forceinline__ void gl_lds16(const void* g, void* l) {
    __builtin_amdgcn_global_load_lds(
        (const __attribute__((address_space(1))) unsigned int*)g,
        (__attribute__((address_space(3))) unsigned int*)l, 16, 0, 0);
}

// ---------------------------------------------------------------------------
// Weights [4096][K] f32 -> permuted SINGLE fp16 [dr][K].
// dr = uc*64 + c (unit uc*16+(c>>2), gate c&3; src row (c&3)*1024+uc*16+(c>>2)).
// Super-chunk (64 k) = 128 B per row, 8 granules — same staging geometry as
// the proven pair kernel.
// ---------------------------------------------------------------------------
__global__ __launch_bounds__(256) void conv_wf16_k(
    const float* __restrict__ src, _Float16* __restrict__ dst, int K, int ks3)
{
    int i  = blockIdx.x * 256 + threadIdx.x;         // piece = 8 elems
    int c  = i & 63;
    int kk = (i >> 6) & ((K >> 3) - 1);
    int uc = i >> (6 + ks3);
    int r  = (c & 3) * 1024 + uc * 16 + (c >> 2);
    const float* s = src + (size_t)r * K + kk * 8;
    f16x8 p;
#pragma unroll
    for (int e = 0; e < 8; ++e) p[e] = (_Float16)s[e];
    *(f16x8*)(dst + (size_t)(uc * 64 + c) * K + kk * 8) = p;
}

// ---------------------------------------------------------------------------
// Activations [R][K] f32 -> fp16 hi/lo PAIR, blocked per 64-k:
// row = R blocks of 256 B: [hi(64 elems) 128B | lo(64) 128B]. Row bytes 4K.
// ---------------------------------------------------------------------------
__global__ __launch_bounds__(256) void conv_af16p_k(
    const float* __restrict__ src, _Float16* __restrict__ dst, int total8, int ks3)
{
    int i = blockIdx.x * 256 + threadIdx.x;
    if (i >= total8) return;
    int K8 = 1 << ks3;                               // K/8
    int r  = i >> ks3;
    int kk = i & (K8 - 1);
    int K  = K8 * 8;
    const float* s = src + (size_t)r * K + kk * 8;
    f16x8 hi, lo;
#pragma unroll
    for (int e = 0; e < 8; ++e) {
        _Float16 h = (_Float16)s[e];
        hi[e] = h;
        lo[e] = (_Float16)(s[e] - (float)h);
    }
    int k0 = kk * 8, q = k0 >> 6, w0 = k0 & 63;
    _Float16* d = dst + (size_t)r * 2 * K + q * 128;
    *(f16x8*)(d + w0)      = hi;
    *(f16x8*)(d + 64 + w0) = lo;
}

// ---------------------------------------------------------------------------
// Fused GEMM + LSTM cell, fp16 mixed-precision variant.
// Block = 64 batch x 64 gate-cols (16 units). grid 512 = 8 bm x 64 uc
// (wg%8 = uc%8 -> B-sharing blocks on one XCD, synchronized walk). 4 waves
// (2m x 2n), wave tile 32x32 (2x2 frags 16x16x32 f16). A = fp16 hi/lo pair
// (exact), B = fp16 single (rel 2^-11) -> 2-term MFMA (ah*b + al*b).
// Super-chunk = 64 k: staged A 16KB (hi 8K + lo 8K planes) + B 8KB = 24KB.
// LDS 3 bufs x 24KB = 72KB -> 2 blocks/CU. 1-superchunk interval, depth-2
// prefetch, vmcnt(6)/(0) ladder. Staged bytes = 0.75x of the pair kernel
// (the ~21 B/cyc/CU staging-fill wall is the binding constraint).
// Cell epilogue in-block; h out as fp16 pair (blocked per-64k layout).
// ---------------------------------------------------------------------------
__global__ __launch_bounds__(256, 2) void lstm_fh(
    const char* __restrict__ a0, long long a0row_b, int k0,
    const char* __restrict__ a1,                     // h pair rows, 4096 B
    const _Float16* __restrict__ w0f,                // permuted fp16, row 2*k0 B
    const _Float16* __restrict__ w1f,                // permuted fp16, row 2048 B
    const float* __restrict__ bias,
    float* __restrict__ cst, _Float16* __restrict__ hout)
{
    extern __shared__ char smem[];                   // 3 * 24576 = 73728
    const int tid  = threadIdx.x;
    const int lane = tid & 63;
    const int w    = tid >> 6;                       // wave 0..3
    const int wm   = w >> 1, wn = w & 1;
    const int wg   = blockIdx.x;
    const int bm   = wg >> 6;                        // 0..7
    const int uc   = wg & 63;                        // 0..63

    const int nA = k0 >> 6;                          // super-chunks in x seg
    const int n  = nA + 16;                          // + recurrent (1024/64)

    // ---- staging geometry ----
    const int rsub = lane >> 3;
    const int slot = lane & 7;
    const int gsw  = slot ^ rsub;                    // XOR-swizzled src granule

    const char* pa0[2]; const char* pa1[2];          // A row base (+gsw)
    const char* pb0[2]; const char* pb1[2];          // B row base (+gsw)
#pragma unroll
    for (int j = 0; j < 2; ++j) {
        int ar = bm * 64 + w * 16 + j * 8 + rsub;
        pa0[j] = a0 + (size_t)ar * a0row_b + gsw * 16;
        pa1[j] = a1 + (size_t)ar * 4096 + gsw * 16;
        int c  = w * 16 + j * 8 + rsub;
        int dr = uc * 64 + c;
        pb0[j] = (const char*)w0f + (size_t)dr * (2 * (size_t)k0) + gsw * 16;
        pb1[j] = (const char*)w1f + (size_t)dr * 2048 + gsw * 16;
    }

    // LDS dests wave-uniform (HW adds lane*16). bufA: hi plane [64][128] @0,
    // lo plane @8192; bufB [64][128] @16384. 6 gl_lds16 per wave per chunk.
    auto stage = [&](int c, int buf) {
        char* bufA = smem + buf * 24576;
        char* bufB = bufA + 16384;
        const char* const* pa = (c < nA) ? pa0 : pa1;
        const char* const* pb = (c < nA) ? pb0 : pb1;
        int cc = (c < nA) ? c : c - nA;
        size_t kbA = (size_t)cc * 256;               // pair block (hi|lo)
        size_t kbB = (size_t)cc * 128;               // single block
#pragma unroll
        for (int j = 0; j < 2; ++j) {
            gl_lds16(pa[j] + kbA,       bufA + w * 2048 + j * 1024);          // hi
            gl_lds16(pa[j] + kbA + 128, bufA + 8192 + w * 2048 + j * 1024);   // lo
            gl_lds16(pb[j] + kbB,       bufB + w * 2048 + j * 1024);
        }
    };

    // ---- fragment geometry ----
    int rA[2], rB[2];
#pragma unroll
    for (int f = 0; f < 2; ++f) {
        rA[f] = wm * 32 + f * 16 + (lane & 15);
        rB[f] = wn * 32 + f * 16 + (lane & 15);
    }
    const int s7 = lane & 7;
    const int g0 = lane >> 4;                        // k-granule group 0..3

    f32x4 acc[2][2];
#pragma unroll
    for (int a = 0; a < 2; ++a)
#pragma unroll
        for (int b = 0; b < 2; ++b)
            acc[a][b] = (f32x4){0.f, 0.f, 0.f, 0.f};

    auto chunk = [&](int c, int buf) {
        char* bufA = smem + buf * 24576;
        char* bufB = bufA + 16384;
        f16x8 ah[2][2], al[2][2], bb[2][2];
#pragma unroll
        for (int f = 0; f < 2; ++f)
#pragma unroll
            for (int s = 0; s < 2; ++s) {
                int gx = ((g0 + s * 4) ^ s7) * 16;
                ah[f][s] = *(const f16x8*)(bufA + rA[f] * 128 + gx);
                al[f][s] = *(const f16x8*)(bufA + 8192 + rA[f] * 128 + gx);
                bb[f][s] = *(const f16x8*)(bufB + rB[f] * 128 + gx);
            }
#pragma unroll
        for (int mf = 0; mf < 2; ++mf)
#pragma unroll
            for (int nf = 0; nf < 2; ++nf)
#pragma unroll
                for (int s = 0; s < 2; ++s) {
                    acc[mf][nf] = __builtin_amdgcn_mfma_f32_16x16x32_f16(
                        ah[mf][s], bb[nf][s], acc[mf][nf], 0, 0, 0);
                    acc[mf][nf] = __builtin_amdgcn_mfma_f32_16x16x32_f16(
                        al[mf][s], bb[nf][s], acc[mf][nf], 0, 0, 0);
                }
    };

    stage(0, 0);
    stage(1, 1);

    for (int i = 0; i < n; ++i) {
        if (i + 1 < n) asm volatile("s_waitcnt vmcnt(6)" ::: "memory");
        else           asm volatile("s_waitcnt vmcnt(0)" ::: "memory");
        __builtin_amdgcn_sched_barrier(0);
        __builtin_amdgcn_s_barrier();
        __builtin_amdgcn_sched_barrier(0);

        if (i + 2 < n) {
            int b2 = i + 2; while (b2 >= 3) b2 -= 3;
            stage(i + 2, b2);
        }

        int bi = i; while (bi >= 3) bi -= 3;
        chunk(i, bi);
        __builtin_amdgcn_sched_barrier(0);
    }

    // ---- epilogue: acc -> LDS scratch [64][SCR] f32 ----
    __syncthreads();
    float* scr = (float*)smem;
#pragma unroll
    for (int mf = 0; mf < 2; ++mf)
#pragma unroll
        for (int nf = 0; nf < 2; ++nf) {
            int row0 = wm * 32 + mf * 16 + (lane >> 4) * 4;   // m89 C layout
            int col  = wn * 32 + nf * 16 + (lane & 15);
#pragma unroll
            for (int j = 0; j < 4; ++j)
                scr[(row0 + j) * SCR + col] = acc[mf][nf][j];
        }
    __syncthreads();

    // ---- in-block cell: 64 rows x 16 units ----
#pragma unroll
    for (int p = 0; p < 4; ++p) {
        int item = p * 256 + tid;
        int u = item & 15;
        int r = item >> 4;                           // 0..63
        f32x4 g4 = *(const f32x4*)(scr + r * SCR + u * 4);
        int gu = uc * 16 + u;
        float gi = g4[0] + bias[gu];
        float gf = g4[1] + bias[H1 + gu];
        float gg = g4[2] + bias[2 * H1 + gu];
        float go = g4[3] + bias[3 * H1 + gu];
        float si = 1.f / (1.f + expf(-gi));
        float sf = 1.f / (1.f + expf(-gf));
        float so = 1.f / (1.f + expf(-go));
        int row_g = bm * 64 + r;
        size_t ci = (size_t)row_g * H1 + gu;
        float cc = sf * cst[ci] + si * tanhf(gg);
        cst[ci] = cc;
        float hv = so * tanhf(cc);
        _Float16 hh = (_Float16)hv;
        size_t hb = (size_t)row_g * 2048 + (gu >> 6) * 128 + (gu & 63);
        hout[hb]      = hh;
        hout[hb + 64] = (_Float16)(hv - (float)hh);
    }
}

// ---------------------------------------------------------------------------
// head on fp16-pair h: 16 lanes per output (one 64-k block each), shfl_xor.
// ---------------------------------------------------------------------------
__global__ __launch_bounds__(256) void head_fh_k(
    const _Float16* __restrict__ hp, const float* __restrict__ W,
    const float* __restrict__ bo, float* __restrict__ out)
{
    int gid = blockIdx.x * 16 + (threadIdx.x >> 4);  // output 0..8191
    int l16 = threadIdx.x & 15;
    int b = gid >> 4, o = gid & 15;
    const _Float16* hr = hp + (size_t)b * 2048 + l16 * 128;
    const float*    wr = W + (size_t)o * H1 + l16 * 64;
    float s = 0.f;
#pragma unroll
    for (int j8 = 0; j8 < 8; ++j8) {
        f16x8 vh = *(const f16x8*)(hr + j8 * 8);
        f16x8 vl = *(const f16x8*)(hr + 64 + j8 * 8);
        const f32x4* wv = (const f32x4*)(wr + j8 * 8);
        f32x4 w0 = wv[0], w1 = wv[1];
#pragma unroll
        for (int e = 0; e < 4; ++e)
            s += ((float)vh[e] + (float)vl[e]) * w0[e];
#pragma unroll
        for (int e = 4; e < 8; ++e)
            s += ((float)vh[e] + (float)vl[e]) * w1[e - 4];
    }
#pragma unroll
    for (int m = 8; m >= 1; m >>= 1)
        s += __shfl_xor(s, m, 16);
    if (l16 == 0) {
        float v = s + bo[o];
        out[(size_t)b * 32 + o]      = v;
        out[(size_t)b * 32 + 16 + o] = v;
    }
}

// ---------------------------------------------------------------------------
// FALLBACK (r9/r10-proven f32 all-LDS path) — runs only if ws too small.
// ---------------------------------------------------------------------------
__global__ __launch_bounds__(256, 1) void lstm_fused_f32(
    const float* __restrict__ a0v, long long arow_b, int k0,
    const float* __restrict__ w0v,
    const float* __restrict__ a1v,
    const float* __restrict__ w1v,
    const float* __restrict__ bias,
    float* __restrict__ cst, float* __restrict__ houtv)
{
    extern __shared__ char smem[];
    const int tid  = threadIdx.x;
    const int lane = tid & 63;
    const int w    = tid >> 6;
    const int wm   = w >> 1, wn = w & 1;
    const int wg   = blockIdx.x;
    const int bm   = wg >> 5;
    const int uc   = wg & 31;

    const int nA = k0 >> 5;
    const int n  = nA + 32;

    const int rsub = lane >> 3;
    const int slot = lane & 7;
    const int gsw  = slot ^ rsub;

    const char* paj0[2]; const char* paj1[2];
    const char* pbj0[4]; const char* pbj1[4];
#pragma unroll
    for (int j = 0; j < 2; ++j) {
        int ar = bm * 64 + w * 16 + j * 8 + rsub;
        paj0[j] = (const char*)a0v + (size_t)ar * arow_b + gsw * 16;
        paj1[j] = (const char*)a1v + (size_t)ar * 4096 + gsw * 16;
    }
#pragma unroll
    for (int j = 0; j < 4; ++j) {
        int c = w * 32 + j * 8 + rsub;
        int br0 = (c & 3) * H1 + uc * 32 + (c >> 2);
        pbj0[j] = (const char*)w0v + (size_t)br0 * (4 * (size_t)k0) + gsw * 16;
        pbj1[j] = (const char*)w1v + (size_t)br0 * 4096 + gsw * 16;
    }

    auto stage = [&](int ii, int buf) {
        char* bufA = smem + buf * 24576;
        char* bufB = bufA + 8192;
        size_t kb = (ii < nA) ? (size_t)ii * 128 : (size_t)(ii - nA) * 128;
        const char* const* pa = (ii < nA) ? paj0 : paj1;
        const char* const* pb = (ii < nA) ? pbj0 : pbj1;
#pragma unroll
        for (int j = 0; j < 2; ++j)
            gl_lds16(pa[j] + kb, bufA + (w * 2 + j) * 1024);
#pragma unroll
        for (int j = 0; j < 4; ++j)
            gl_lds16(pb[j] + kb, bufB + (w * 4 + j) * 1024);
    };

    int rAv[2], rBv[4];
#pragma unroll
    for (int f = 0; f < 2; ++f) rAv[f] = wm * 32 + f * 16 + (lane & 15);
#pragma unroll
    for (int f = 0; f < 4; ++f) rBv[f] = wn * 64 + f * 16 + (lane & 15);
    const int s7 = lane & 7;
    const int g0 = lane >> 4;

    f32x4 acc[2][4];
#pragma unroll
    for (int mf = 0; mf < 2; ++mf)
#pragma unroll
        for (int nf = 0; nf < 4; ++nf)
            acc[mf][nf] = (f32x4){0.f, 0.f, 0.f, 0.f};

    stage(0, 0); stage(1, 1); stage(2, 2); stage(3, 3); stage(4, 4);

    int buf = 0;
    for (int i = 0; i < n; ++i) {
        const int rem = n - i;
        if (rem >= 5)      asm volatile("s_waitcnt vmcnt(24)" ::: "memory");
        else if (rem == 4) asm volatile("s_waitcnt vmcnt(18)" ::: "memory");
        else if (rem == 3) asm volatile("s_waitcnt vmcnt(12)" ::: "memory");
        else if (rem == 2) asm volatile("s_waitcnt vmcnt(6)"  ::: "memory");
        else               asm volatile("s_waitcnt vmcnt(0)"  ::: "memory");
        __builtin_amdgcn_sched_barrier(0);
        __builtin_amdgcn_s_barrier();
        __builtin_amdgcn_sched_barrier(0);

        if (i + 5 < n) {
            int b5 = buf + 5; if (b5 >= 6) b5 -= 6;
            stage(i + 5, b5);
        }

        char* bufA = smem + buf * 24576;
        char* bufB = bufA + 8192;

        bf16x8 ah[2], al[2], bh[4], bl[4];
#pragma unroll
        for (int f = 0; f < 2; ++f) {
            f32x4 v0 = *(const f32x4*)(bufA + rAv[f] * 128 + ((2 * g0    ) ^ s7) * 16);
            f32x4 v1 = *(const f32x4*)(bufA + rAv[f] * 128 + ((2 * g0 + 1) ^ s7) * 16);
#pragma unroll
            for (int e = 0; e < 4; ++e) {
                __bf16 h0 = (__bf16)v0[e];
                ah[f][e] = h0; al[f][e] = (__bf16)(v0[e] - (float)h0);
                __bf16 h1 = (__bf16)v1[e];
                ah[f][e + 4] = h1; al[f][e + 4] = (__bf16)(v1[e] - (float)h1);
            }
        }
#pragma unroll
        for (int f = 0; f < 4; ++f) {
            f32x4 u0 = *(const f32x4*)(bufB + rBv[f] * 128 + ((2 * g0    ) ^ s7) * 16);
            f32x4 u1 = *(const f32x4*)(bufB + rBv[f] * 128 + ((2 * g0 + 1) ^ s7) * 16);
#pragma unroll
            for (int e = 0; e < 4; ++e) {
                __bf16 h0 = (__bf16)u0[e];
                bh[f][e] = h0; bl[f][e] = (__bf16)(u0[e] - (float)h0);
                __bf16 h1 = (__bf16)u1[e];
                bh[f][e + 4] = h1; bl[f][e + 4] = (__bf16)(u1[e] - (float)h1);
            }
        }
#pragma unroll
        for (int mf = 0; mf < 2; ++mf)
#pragma unroll
            for (int nf = 0; nf < 4; ++nf) {
                acc[mf][nf] = __builtin_amdgcn_mfma_f32_16x16x32_bf16(
                    ah[mf], bh[nf], acc[mf][nf], 0, 0, 0);
                acc[mf][nf] = __builtin_amdgcn_mfma_f32_16x16x32_bf16(
                    ah[mf], bl[nf], acc[mf][nf], 0, 0, 0);
                acc[mf][nf] = __builtin_amdgcn_mfma_f32_16x16x32_bf16(
                    al[mf], bh[nf], acc[mf][nf], 0, 0, 0);
            }
        __builtin_amdgcn_sched_barrier(0);
        buf = buf + 1; if (buf >= 6) buf -= 6;
    }

    __syncthreads();
    float* scr = (float*)smem;
#pragma unroll
    for (int mf = 0; mf < 2; ++mf)
#pragma unroll
        for (int nf = 0; nf < 4; ++nf) {
            int row0 = wm * 32 + mf * 16 + (lane >> 4) * 4;
            int col  = wn * 64 + nf * 16 + (lane & 15);
#pragma unroll
            for (int j = 0; j < 4; ++j)
                scr[(row0 + j) * 128 + col] = acc[mf][nf][j];
        }
    __syncthreads();

#pragma unroll
    for (int p = 0; p < 8; ++p) {
        int item = p * 256 + tid;
        int u = item & 31;
        int r = item >> 5;
        f32x4 g4 = *(const f32x4*)(scr + r * 128 + u * 4);
        int gu = uc * 32 + u;
        float gi = g4[0] + bias[gu];
        float gf = g4[1] + bias[H1 + gu];
        float gg = g4[2] + bias[2 * H1 + gu];
        float go = g4[3] + bias[3 * H1 + gu];
        float si = 1.f / (1.f + expf(-gi));
        float sf = 1.f / (1.f + expf(-gf));
        float so = 1.f / (1.f + expf(-go));
        size_t ci = (size_t)(bm * 64 + r) * H1 + gu;
        float cc = sf * cst[ci] + si * tanhf(gg);
        cst[ci] = cc;
        houtv[ci] = so * tanhf(cc);
    }
}

__global__ __launch_bounds__(256) void head_k(
    const float* __restrict__ h, const float* __restrict__ W,
    const float* __restrict__ bo, float* __restrict__ out)
{
    int idx = blockIdx.x * 256 + threadIdx.x;
    int b = idx >> 4, o = idx & 15;
    const f32x4* hv = (const f32x4*)(h + (size_t)b * H1);
    const f32x4* wv = (const f32x4*)(W + (size_t)o * H1);
    float s = bo[o];
#pragma unroll 4
    for (int k = 0; k < H1 / 4; ++k) {
        f32x4 a = hv[k];
        f32x4 wq = wv[k];
        s += a[0] * wq[0] + a[1] * wq[1] + a[2] * wq[2] + a[3] * wq[3];
    }
    out[(size_t)b * 32 + o]      = s;
    out[(size_t)b * 32 + 16 + o] = s;
}

// ===========================================================================
extern "C" void kernel_launch(void* const* d_in, const int* in_sizes, int n_in,
                              void* d_out, int out_size, void* d_ws, size_t ws_size,
                              hipStream_t stream)
{
    const float* x    = (const float*)d_in[0];
    const float* Wih0 = (const float*)d_in[1];
    const float* Whh0 = (const float*)d_in[2];
    const float* b0   = (const float*)d_in[3];
    const float* Wih1 = (const float*)d_in[4];
    const float* Whh1 = (const float*)d_in[5];
    const float* b1   = (const float*)d_in[6];
    const float* dWih = (const float*)d_in[7];
    const float* dWhh = (const float*)d_in[8];
    const float* db   = (const float*)d_in[9];
    const float* Wout = (const float*)d_in[10];
    const float* bout = (const float*)d_in[11];

    dim3 blk(256);
    const size_t WF_SMALL = (size_t)4096 * 128 * 2;    // 1MB  fp16 K=128
    const size_t WF_BIG   = (size_t)4096 * 1024 * 2;   // 8MB  fp16 K=1024
    const size_t XPB      = (size_t)BATCH * SEQ * 256 * 2; // 16MB x pair
    const size_t HPB      = (size_t)BATCH * 2048 * 2;  // 2MB  h pair
    const size_t CSZ      = (size_t)BATCH * H1;        // elems
    const size_t NEED1    = WF_SMALL + 7 * WF_BIG + XPB + 4 * HPB + 2 * CSZ * 4;
    const size_t SMF      = 73728;                     // lstm_fh dynamic LDS

    const float* dWih1 = dWih + (size_t)FOURH * H1;
    const float* dWhh1 = dWhh + (size_t)FOURH * H1;

    if (ws_size >= NEED1) {
        // ---------------- fp16 mixed path ----------------
        char* wsb = (char*)d_ws;
        _Float16* Wih0f  = (_Float16*)wsb;
        _Float16* Whh0f  = (_Float16*)(wsb + WF_SMALL);
        _Float16* Wih1f  = (_Float16*)(wsb + WF_SMALL + WF_BIG);
        _Float16* Whh1f  = (_Float16*)(wsb + WF_SMALL + 2 * WF_BIG);
        _Float16* dWih0f = (_Float16*)(wsb + WF_SMALL + 3 * WF_BIG);
        _Float16* dWhh0f = (_Float16*)(wsb + WF_SMALL + 4 * WF_BIG);
        _Float16* dWih1f = (_Float16*)(wsb + WF_SMALL + 5 * WF_BIG);
        _Float16* dWhh1f = (_Float16*)(wsb + WF_SMALL + 6 * WF_BIG);
        char* sb = wsb + WF_SMALL + 7 * WF_BIG;
        _Float16* xp   = (_Float16*)sb;
        _Float16* hp0a = (_Float16*)(sb + XPB);
        _Float16* hp0b = (_Float16*)(sb + XPB + HPB);
        _Float16* hp1a = (_Float16*)(sb + XPB + 2 * HPB);
        _Float16* hp1b = (_Float16*)(sb + XPB + 3 * HPB);
        float*    c0   = (float*)(sb + XPB + 4 * HPB);
        float*    c1   = c0 + CSZ;

        auto convw = [&](const float* s, _Float16* d, int K, int ks3) {
            int total = 4096 * (K >> 3);
            conv_wf16_k<<<dim3(total / 256), blk, 0, stream>>>(s, d, K, ks3);
        };
        convw(Wih0, Wih0f, 128, 4);
        convw(Whh0, Whh0f, 1024, 7);
        convw(Wih1, Wih1f, 1024, 7);
        convw(Whh1, Whh1f, 1024, 7);
        convw(dWih,  dWih0f, 1024, 7);
        convw(dWih1, dWih1f, 1024, 7);
        convw(dWhh,  dWhh0f, 1024, 7);
        convw(dWhh1, dWhh1f, 1024, 7);
        {
            int total8 = BATCH * SEQ * 16;           // rows 32768, K=128
            conv_af16p_k<<<dim3((total8 + 255) / 256), blk, 0, stream>>>(
                x, xp, total8, 4);
        }

        hipMemsetAsync(hp0a, 0, 4 * HPB + 2 * CSZ * 4, stream);

        (void)hipFuncSetAttribute(reinterpret_cast<const void*>(&lstm_fh),
                                  hipFuncAttributeMaxDynamicSharedMemorySize, SMF);

        dim3 fgrid(512);
        _Float16 *hc = hp0a, *hn = hp0b, *h1c = hp1a, *h1n = hp1b;
        const long long XROW = (long long)(SEQ * 256 * 2);  // x pair row bytes
        for (int t = 0; t < SEQ; ++t) {
            lstm_fh<<<fgrid, blk, SMF, stream>>>(
                (const char*)xp + (size_t)t * 512, XROW, DIN,
                (const char*)hc, Wih0f, Whh0f, b0, c0, hn);
            lstm_fh<<<fgrid, blk, SMF, stream>>>(
                (const char*)hn, 4096LL, H1,
                (const char*)h1c, Wih1f, Whh1f, b1, c1, h1n);
            _Float16* t0 = hc; hc = hn; hn = t0;
            _Float16* t1 = h1c; h1c = h1n; h1n = t1;
        }
        for (int s = 0; s < TDEC; ++s) {
            lstm_fh<<<fgrid, blk, SMF, stream>>>(
                (const char*)h1c, 4096LL, H1,
                (const char*)hc, dWih0f, dWhh0f, db, c0, hn);
            lstm_fh<<<fgrid, blk, SMF, stream>>>(
                (const char*)hn, 4096LL, H1,
                (const char*)h1c, dWih1f, dWhh1f, db + FOURH, c1, h1n);
            _Float16* t0 = hc; hc = hn; hn = t0;
            _Float16* t1 = h1c; h1c = h1n; h1n = t1;
        }
        head_fh_k<<<dim3(512), blk, 0, stream>>>(h1c, Wout, bout, (float*)d_out);
    } else {
        // ---------------- f32 fallback (proven) ----------------
        float* h0a = (float*)d_ws;
        float* h0b = h0a + CSZ;
        float* h1a = h0b + CSZ;
        float* h1b = h1a + CSZ;
        float* c0  = h1b + CSZ;
        float* c1  = c0 + CSZ;
        hipMemsetAsync(h0a, 0, 6 * CSZ * 4, stream);

        (void)hipFuncSetAttribute(reinterpret_cast<const void*>(&lstm_fused_f32),
                                  hipFuncAttributeMaxDynamicSharedMemorySize, 147456);

        dim3 oldgrid(256);
        float *hc = h0a, *hn = h0b, *h1c = h1a, *h1n = h1b;
        for (int t = 0; t < SEQ; ++t) {
            lstm_fused_f32<<<oldgrid, blk, 147456, stream>>>(
                x + (size_t)t * DIN, (long long)(SEQ * DIN * 4), DIN, Wih0,
                hc, Whh0, b0, c0, hn);
            lstm_fused_f32<<<oldgrid, blk, 147456, stream>>>(
                hn, 4096LL, H1, Wih1, h1c, Whh1, b1, c1, h1n);
            float* t0 = hc; hc = hn; hn = t0;
            float* t1 = h1c; h1c = h1n; h1n = t1;
        }
        for (int s = 0; s < TDEC; ++s) {
            lstm_fused_f32<<<oldgrid, blk, 147456, stream>>>(
                h1c, 4096LL, H1, dWih, hc, dWhh, db, c0, hn);
            lstm_fused_f32<<<oldgrid, blk, 147456, stream>>>(
                hn, 4096LL, H1, dWih1, h1c, dWhh1, db + FOURH, c1, h1n);
            float* t0 = hc; hc = hn; hn = t0;
            float* t1 = h1c; h1c = h1n; h1n = t1;
        }
        head_k<<<dim3(32), blk, 0, stream>>>(h1c, Wout, bout, (float*)d_out);
    }
}

// Round 19
// 2336.144 us; speedup vs baseline: 1.9473x; 1.4090x over previous
//
#include <hip/hip_runtime.h>
#include <hip/hip_bf16.h>

#define H1 1024
#define FOURH 4096
#define BATCH 512
#define SEQ 64
#define DIN 128
#define TDEC 8
#define SCR 68

typedef float f32x4 __attribute__((ext_vector_type(4)));
typedef _Float16 f16x8 __attribute__((ext_vector_type(8)));
typedef __bf16 bf16x8 __attribute__((ext_vector_type(8)));

// global->LDS direct, 16B per lane. LDS dest is wave-uniform base + lane*16.
__device__ __forceinline__ void gl_lds16(const void* g, void* l) {
    __builtin_amdgcn_global_load_lds(
        (const __attribute__((address_space(1))) unsigned int*)g,
        (__attribute__((address_space(3))) unsigned int*)l, 16, 0, 0);
}

// ---------------------------------------------------------------------------
// Weights [4096][K] f32 -> permuted SINGLE fp16 [dr][K].
// dr = uc*64 + c (unit uc*16+(c>>2), gate c&3; src row (c&3)*1024+uc*16+(c>>2)).
// ---------------------------------------------------------------------------
__global__ __launch_bounds__(256) void conv_wf16_k(
    const float* __restrict__ src, _Float16* __restrict__ dst, int K, int ks3)
{
    int i  = blockIdx.x * 256 + threadIdx.x;         // piece = 8 elems
    int c  = i & 63;
    int kk = (i >> 6) & ((K >> 3) - 1);
    int uc = i >> (6 + ks3);
    int r  = (c & 3) * 1024 + uc * 16 + (c >> 2);
    const float* s = src + (size_t)r * K + kk * 8;
    f16x8 p;
#pragma unroll
    for (int e = 0; e < 8; ++e) p[e] = (_Float16)s[e];
    *(f16x8*)(dst + (size_t)(uc * 64 + c) * K + kk * 8) = p;
}

// x [R][K] f32 -> single fp16, plain row layout.
__global__ __launch_bounds__(256) void conv_xf16_k(
    const float* __restrict__ src, _Float16* __restrict__ dst, int total8)
{
    int i = blockIdx.x * 256 + threadIdx.x;
    if (i >= total8) return;
    const float* s = src + (size_t)i * 8;
    f16x8 p;
#pragma unroll
    for (int e = 0; e < 8; ++e) p[e] = (_Float16)s[e];
    *(f16x8*)(dst + (size_t)i * 8) = p;
}

// ---------------------------------------------------------------------------
// Fused GEMM + LSTM cell, all-single-fp16 operands (c state stays f32).
// Block = 64 batch x 64 gate-cols (16 units). grid 512 = 8 bm x 64 uc
// (wg%8 = uc%8 -> B-sharing blocks on one XCD, synchronized walk). 4 waves
// (2m x 2n), wave tile 32x32 (2x2 frags of 16x16x32 f16), 1-term MFMA.
// Super-chunk = 64 k: A 8KB + B 8KB = 16KB staged (0.67x of r18; the
// ~21 B/cyc/CU staging-fill wall is the binding constraint). LDS ring
// 3 x 16KB = 48KB static -> 2 blocks/CU. Depth-2 prefetch, vmcnt(4)/(0).
// Error budget: A,B rel 2^-11 each; measured B-only cost +2.44e-4 ->
// predicted total ~1e-3 < 2.34e-3 threshold. c remains f32 (exact path).
// Cell epilogue in-block; h out single fp16 [row][1024].
// ---------------------------------------------------------------------------
__global__ __launch_bounds__(256, 2) void lstm_fs(
    const char* __restrict__ a0, long long a0row_b, int k0,
    const char* __restrict__ a1,                     // h fp16, row 2048 B
    const _Float16* __restrict__ w0f,                // permuted fp16, row 2*k0 B
    const _Float16* __restrict__ w1f,                // permuted fp16, row 2048 B
    const float* __restrict__ bias,
    float* __restrict__ cst, _Float16* __restrict__ hout)
{
    __shared__ char smem[49152];                     // 3 bufs x (A 8KB + B 8KB)
    const int tid  = threadIdx.x;
    const int lane = tid & 63;
    const int w    = tid >> 6;                       // wave 0..3
    const int wm   = w >> 1, wn = w & 1;
    const int wg   = blockIdx.x;
    const int bm   = wg >> 6;                        // 0..7
    const int uc   = wg & 63;                        // 0..63

    const int nA = k0 >> 6;                          // super-chunks in seg 0
    const int n  = nA + 16;                          // + recurrent (1024/64)

    // ---- staging geometry ----
    const int rsub = lane >> 3;
    const int slot = lane & 7;
    const int gsw  = slot ^ rsub;                    // XOR-swizzled src granule

    const char* pa0[2]; const char* pa1[2];
    const char* pb0[2]; const char* pb1[2];
#pragma unroll
    for (int j = 0; j < 2; ++j) {
        int ar = bm * 64 + w * 16 + j * 8 + rsub;
        pa0[j] = a0 + (size_t)ar * a0row_b + gsw * 16;
        pa1[j] = a1 + (size_t)ar * 2048 + gsw * 16;
        int c  = w * 16 + j * 8 + rsub;
        int dr = uc * 64 + c;
        pb0[j] = (const char*)w0f + (size_t)dr * (2 * (size_t)k0) + gsw * 16;
        pb1[j] = (const char*)w1f + (size_t)dr * 2048 + gsw * 16;
    }

    // LDS dests wave-uniform (HW adds lane*16); wave w sub-block j covers
    // rows w*16+j*8..+8 (1024B per gl_lds16). 4 gl_lds16 per wave per chunk.
    auto stage = [&](int c, int buf) {
        char* bufA = smem + buf * 16384;
        char* bufB = bufA + 8192;
        const char* const* pa = (c < nA) ? pa0 : pa1;
        const char* const* pb = (c < nA) ? pb0 : pb1;
        size_t kb = (size_t)((c < nA) ? c : c - nA) * 128;
#pragma unroll
        for (int j = 0; j < 2; ++j) {
            gl_lds16(pa[j] + kb, bufA + w * 2048 + j * 1024);
            gl_lds16(pb[j] + kb, bufB + w * 2048 + j * 1024);
        }
    };

    // ---- fragment geometry ----
    int rA[2], rB[2];
#pragma unroll
    for (int f = 0; f < 2; ++f) {
        rA[f] = wm * 32 + f * 16 + (lane & 15);
        rB[f] = wn * 32 + f * 16 + (lane & 15);
    }
    const int s7 = lane & 7;
    const int g0 = lane >> 4;                        // k-granule group 0..3

    f32x4 acc[2][2];
#pragma unroll
    for (int a = 0; a < 2; ++a)
#pragma unroll
        for (int b = 0; b < 2; ++b)
            acc[a][b] = (f32x4){0.f, 0.f, 0.f, 0.f};

    auto chunk = [&](int buf) {
        char* bufA = smem + buf * 16384;
        char* bufB = bufA + 8192;
        f16x8 aa[2][2], bb[2][2];
#pragma unroll
        for (int f = 0; f < 2; ++f)
#pragma unroll
            for (int s = 0; s < 2; ++s) {
                int gx = ((g0 + s * 4) ^ s7) * 16;
                aa[f][s] = *(const f16x8*)(bufA + rA[f] * 128 + gx);
                bb[f][s] = *(const f16x8*)(bufB + rB[f] * 128 + gx);
            }
#pragma unroll
        for (int mf = 0; mf < 2; ++mf)
#pragma unroll
            for (int nf = 0; nf < 2; ++nf)
#pragma unroll
                for (int s = 0; s < 2; ++s)
                    acc[mf][nf] = __builtin_amdgcn_mfma_f32_16x16x32_f16(
                        aa[mf][s], bb[nf][s], acc[mf][nf], 0, 0, 0);
    };

    stage(0, 0);
    stage(1, 1);

    for (int i = 0; i < n; ++i) {
        if (i + 1 < n) asm volatile("s_waitcnt vmcnt(4)" ::: "memory");
        else           asm volatile("s_waitcnt vmcnt(0)" ::: "memory");
        __builtin_amdgcn_sched_barrier(0);
        __builtin_amdgcn_s_barrier();
        __builtin_amdgcn_sched_barrier(0);

        if (i + 2 < n) {
            int b2 = i + 2; while (b2 >= 3) b2 -= 3;
            stage(i + 2, b2);
        }

        int bi = i; while (bi >= 3) bi -= 3;
        chunk(bi);
        __builtin_amdgcn_sched_barrier(0);
    }

    // ---- epilogue: acc -> LDS scratch [64][SCR] f32 ----
    __syncthreads();
    float* scr = (float*)smem;
#pragma unroll
    for (int mf = 0; mf < 2; ++mf)
#pragma unroll
        for (int nf = 0; nf < 2; ++nf) {
            int row0 = wm * 32 + mf * 16 + (lane >> 4) * 4;   // m89 C layout
            int col  = wn * 32 + nf * 16 + (lane & 15);
#pragma unroll
            for (int j = 0; j < 4; ++j)
                scr[(row0 + j) * SCR + col] = acc[mf][nf][j];
        }
    __syncthreads();

    // ---- in-block cell: 64 rows x 16 units ----
#pragma unroll
    for (int p = 0; p < 4; ++p) {
        int item = p * 256 + tid;
        int u = item & 15;
        int r = item >> 4;                           // 0..63
        f32x4 g4 = *(const f32x4*)(scr + r * SCR + u * 4);
        int gu = uc * 16 + u;
        float gi = g4[0] + bias[gu];
        float gf = g4[1] + bias[H1 + gu];
        float gg = g4[2] + bias[2 * H1 + gu];
        float go = g4[3] + bias[3 * H1 + gu];
        float si = 1.f / (1.f + expf(-gi));
        float sf = 1.f / (1.f + expf(-gf));
        float so = 1.f / (1.f + expf(-go));
        int row_g = bm * 64 + r;
        size_t ci = (size_t)row_g * H1 + gu;
        float cc = sf * cst[ci] + si * tanhf(gg);
        cst[ci] = cc;
        hout[(size_t)row_g * H1 + gu] = (_Float16)(so * tanhf(cc));
    }
}

// ---------------------------------------------------------------------------
// head on fp16 h: 16 lanes per output (64 elems each), shfl_xor reduce.
// ---------------------------------------------------------------------------
__global__ __launch_bounds__(256) void head_fs_k(
    const _Float16* __restrict__ hp, const float* __restrict__ W,
    const float* __restrict__ bo, float* __restrict__ out)
{
    int gid = blockIdx.x * 16 + (threadIdx.x >> 4);  // output 0..8191
    int l16 = threadIdx.x & 15;
    int b = gid >> 4, o = gid & 15;
    const _Float16* hr = hp + (size_t)b * H1 + l16 * 64;
    const float*    wr = W + (size_t)o * H1 + l16 * 64;
    float s = 0.f;
#pragma unroll
    for (int j8 = 0; j8 < 8; ++j8) {
        f16x8 v = *(const f16x8*)(hr + j8 * 8);
        const f32x4* wv = (const f32x4*)(wr + j8 * 8);
        f32x4 w0 = wv[0], w1 = wv[1];
#pragma unroll
        for (int e = 0; e < 4; ++e)
            s += (float)v[e] * w0[e];
#pragma unroll
        for (int e = 4; e < 8; ++e)
            s += (float)v[e] * w1[e - 4];
    }
#pragma unroll
    for (int m = 8; m >= 1; m >>= 1)
        s += __shfl_xor(s, m, 16);
    if (l16 == 0) {
        float v = s + bo[o];
        out[(size_t)b * 32 + o]      = v;
        out[(size_t)b * 32 + 16 + o] = v;
    }
}

// ---------------------------------------------------------------------------
// FALLBACK (r9/r10-proven f32 all-LDS path) — runs only if ws too small.
// ---------------------------------------------------------------------------
__global__ __launch_bounds__(256, 1) void lstm_fused_f32(
    const float* __restrict__ a0v, long long arow_b, int k0,
    const float* __restrict__ w0v,
    const float* __restrict__ a1v,
    const float* __restrict__ w1v,
    const float* __restrict__ bias,
    float* __restrict__ cst, float* __restrict__ houtv)
{
    extern __shared__ char smem[];
    const int tid  = threadIdx.x;
    const int lane = tid & 63;
    const int w    = tid >> 6;
    const int wm   = w >> 1, wn = w & 1;
    const int wg   = blockIdx.x;
    const int bm   = wg >> 5;
    const int uc   = wg & 31;

    const int nA = k0 >> 5;
    const int n  = nA + 32;

    const int rsub = lane >> 3;
    const int slot = lane & 7;
    const int gsw  = slot ^ rsub;

    const char* paj0[2]; const char* paj1[2];
    const char* pbj0[4]; const char* pbj1[4];
#pragma unroll
    for (int j = 0; j < 2; ++j) {
        int ar = bm * 64 + w * 16 + j * 8 + rsub;
        paj0[j] = (const char*)a0v + (size_t)ar * arow_b + gsw * 16;
        paj1[j] = (const char*)a1v + (size_t)ar * 4096 + gsw * 16;
    }
#pragma unroll
    for (int j = 0; j < 4; ++j) {
        int c = w * 32 + j * 8 + rsub;
        int br0 = (c & 3) * H1 + uc * 32 + (c >> 2);
        pbj0[j] = (const char*)w0v + (size_t)br0 * (4 * (size_t)k0) + gsw * 16;
        pbj1[j] = (const char*)w1v + (size_t)br0 * 4096 + gsw * 16;
    }

    auto stage = [&](int ii, int buf) {
        char* bufA = smem + buf * 24576;
        char* bufB = bufA + 8192;
        size_t kb = (ii < nA) ? (size_t)ii * 128 : (size_t)(ii - nA) * 128;
        const char* const* pa = (ii < nA) ? paj0 : paj1;
        const char* const* pb = (ii < nA) ? pbj0 : pbj1;
#pragma unroll
        for (int j = 0; j < 2; ++j)
            gl_lds16(pa[j] + kb, bufA + (w * 2 + j) * 1024);
#pragma unroll
        for (int j = 0; j < 4; ++j)
            gl_lds16(pb[j] + kb, bufB + (w * 4 + j) * 1024);
    };

    int rAv[2], rBv[4];
#pragma unroll
    for (int f = 0; f < 2; ++f) rAv[f] = wm * 32 + f * 16 + (lane & 15);
#pragma unroll
    for (int f = 0; f < 4; ++f) rBv[f] = wn * 64 + f * 16 + (lane & 15);
    const int s7 = lane & 7;
    const int g0 = lane >> 4;

    f32x4 acc[2][4];
#pragma unroll
    for (int mf = 0; mf < 2; ++mf)
#pragma unroll
        for (int nf = 0; nf < 4; ++nf)
            acc[mf][nf] = (f32x4){0.f, 0.f, 0.f, 0.f};

    stage(0, 0); stage(1, 1); stage(2, 2); stage(3, 3); stage(4, 4);

    int buf = 0;
    for (int i = 0; i < n; ++i) {
        const int rem = n - i;
        if (rem >= 5)      asm volatile("s_waitcnt vmcnt(24)" ::: "memory");
        else if (rem == 4) asm volatile("s_waitcnt vmcnt(18)" ::: "memory");
        else if (rem == 3) asm volatile("s_waitcnt vmcnt(12)" ::: "memory");
        else if (rem == 2) asm volatile("s_waitcnt vmcnt(6)"  ::: "memory");
        else               asm volatile("s_waitcnt vmcnt(0)"  ::: "memory");
        __builtin_amdgcn_sched_barrier(0);
        __builtin_amdgcn_s_barrier();
        __builtin_amdgcn_sched_barrier(0);

        if (i + 5 < n) {
            int b5 = buf + 5; if (b5 >= 6) b5 -= 6;
            stage(i + 5, b5);
        }

        char* bufA = smem + buf * 24576;
        char* bufB = bufA + 8192;

        bf16x8 ah[2], al[2], bh[4], bl[4];
#pragma unroll
        for (int f = 0; f < 2; ++f) {
            f32x4 v0 = *(const f32x4*)(bufA + rAv[f] * 128 + ((2 * g0    ) ^ s7) * 16);
            f32x4 v1 = *(const f32x4*)(bufA + rAv[f] * 128 + ((2 * g0 + 1) ^ s7) * 16);
#pragma unroll
            for (int e = 0; e < 4; ++e) {
                __bf16 h0 = (__bf16)v0[e];
                ah[f][e] = h0; al[f][e] = (__bf16)(v0[e] - (float)h0);
                __bf16 h1 = (__bf16)v1[e];
                ah[f][e + 4] = h1; al[f][e + 4] = (__bf16)(v1[e] - (float)h1);
            }
        }
#pragma unroll
        for (int f = 0; f < 4; ++f) {
            f32x4 u0 = *(const f32x4*)(bufB + rBv[f] * 128 + ((2 * g0    ) ^ s7) * 16);
            f32x4 u1 = *(const f32x4*)(bufB + rBv[f] * 128 + ((2 * g0 + 1) ^ s7) * 16);
#pragma unroll
            for (int e = 0; e < 4; ++e) {
                __bf16 h0 = (__bf16)u0[e];
                bh[f][e] = h0; bl[f][e] = (__bf16)(u0[e] - (float)h0);
                __bf16 h1 = (__bf16)u1[e];
                bh[f][e + 4] = h1; bl[f][e + 4] = (__bf16)(u1[e] - (float)h1);
            }
        }
#pragma unroll
        for (int mf = 0; mf < 2; ++mf)
#pragma unroll
            for (int nf = 0; nf < 4; ++nf) {
                acc[mf][nf] = __builtin_amdgcn_mfma_f32_16x16x32_bf16(
                    ah[mf], bh[nf], acc[mf][nf], 0, 0, 0);
                acc[mf][nf] = __builtin_amdgcn_mfma_f32_16x16x32_bf16(
                    ah[mf], bl[nf], acc[mf][nf], 0, 0, 0);
                acc[mf][nf] = __builtin_amdgcn_mfma_f32_16x16x32_bf16(
                    al[mf], bh[nf], acc[mf][nf], 0, 0, 0);
            }
        __builtin_amdgcn_sched_barrier(0);
        buf = buf + 1; if (buf >= 6) buf -= 6;
    }

    __syncthreads();
    float* scr = (float*)smem;
#pragma unroll
    for (int mf = 0; mf < 2; ++mf)
#pragma unroll
        for (int nf = 0; nf < 4; ++nf) {
            int row0 = wm * 32 + mf * 16 + (lane >> 4) * 4;
            int col  = wn * 64 + nf * 16 + (lane & 15);
#pragma unroll
            for (int j = 0; j < 4; ++j)
                scr[(row0 + j) * 128 + col] = acc[mf][nf][j];
        }
    __syncthreads();

#pragma unroll
    for (int p = 0; p < 8; ++p) {
        int item = p * 256 + tid;
        int u = item & 31;
        int r = item >> 5;
        f32x4 g4 = *(const f32x4*)(scr + r * 128 + u * 4);
        int gu = uc * 32 + u;
        float gi = g4[0] + bias[gu];
        float gf = g4[1] + bias[H1 + gu];
        float gg = g4[2] + bias[2 * H1 + gu];
        float go = g4[3] + bias[3 * H1 + gu];
        float si = 1.f / (1.f + expf(-gi));
        float sf = 1.f / (1.f + expf(-gf));
        float so = 1.f / (1.f + expf(-go));
        size_t ci = (size_t)(bm * 64 + r) * H1 + gu;
        float cc = sf * cst[ci] + si * tanhf(gg);
        cst[ci] = cc;
        houtv[ci] = so * tanhf(cc);
    }
}

__global__ __launch_bounds__(256) void head_k(
    const float* __restrict__ h, const float* __restrict__ W,
    const float* __restrict__ bo, float* __restrict__ out)
{
    int idx = blockIdx.x * 256 + threadIdx.x;
    int b = idx >> 4, o = idx & 15;
    const f32x4* hv = (const f32x4*)(h + (size_t)b * H1);
    const f32x4* wv = (const f32x4*)(W + (size_t)o * H1);
    float s = bo[o];
#pragma unroll 4
    for (int k = 0; k < H1 / 4; ++k) {
        f32x4 a = hv[k];
        f32x4 wq = wv[k];
        s += a[0] * wq[0] + a[1] * wq[1] + a[2] * wq[2] + a[3] * wq[3];
    }
    out[(size_t)b * 32 + o]      = s;
    out[(size_t)b * 32 + 16 + o] = s;
}

// ===========================================================================
extern "C" void kernel_launch(void* const* d_in, const int* in_sizes, int n_in,
                              void* d_out, int out_size, void* d_ws, size_t ws_size,
                              hipStream_t stream)
{
    const float* x    = (const float*)d_in[0];
    const float* Wih0 = (const float*)d_in[1];
    const float* Whh0 = (const float*)d_in[2];
    const float* b0   = (const float*)d_in[3];
    const float* Wih1 = (const float*)d_in[4];
    const float* Whh1 = (const float*)d_in[5];
    const float* b1   = (const float*)d_in[6];
    const float* dWih = (const float*)d_in[7];
    const float* dWhh = (const float*)d_in[8];
    const float* db   = (const float*)d_in[9];
    const float* Wout = (const float*)d_in[10];
    const float* bout = (const float*)d_in[11];

    dim3 blk(256);
    const size_t WF_SMALL = (size_t)4096 * 128 * 2;    // 1MB  fp16 K=128
    const size_t WF_BIG   = (size_t)4096 * 1024 * 2;   // 8MB  fp16 K=1024
    const size_t XSB      = (size_t)BATCH * SEQ * 128 * 2; // 8MB x fp16
    const size_t HSB      = (size_t)BATCH * H1 * 2;    // 1MB  h fp16
    const size_t CSZ      = (size_t)BATCH * H1;        // elems
    const size_t NEED1    = WF_SMALL + 7 * WF_BIG + XSB + 4 * HSB + 2 * CSZ * 4;

    const float* dWih1 = dWih + (size_t)FOURH * H1;
    const float* dWhh1 = dWhh + (size_t)FOURH * H1;

    if (ws_size >= NEED1) {
        // ---------------- fp16 single path ----------------
        char* wsb = (char*)d_ws;
        _Float16* Wih0f  = (_Float16*)wsb;
        _Float16* Whh0f  = (_Float16*)(wsb + WF_SMALL);
        _Float16* Wih1f  = (_Float16*)(wsb + WF_SMALL + WF_BIG);
        _Float16* Whh1f  = (_Float16*)(wsb + WF_SMALL + 2 * WF_BIG);
        _Float16* dWih0f = (_Float16*)(wsb + WF_SMALL + 3 * WF_BIG);
        _Float16* dWhh0f = (_Float16*)(wsb + WF_SMALL + 4 * WF_BIG);
        _Float16* dWih1f = (_Float16*)(wsb + WF_SMALL + 5 * WF_BIG);
        _Float16* dWhh1f = (_Float16*)(wsb + WF_SMALL + 6 * WF_BIG);
        char* sb = wsb + WF_SMALL + 7 * WF_BIG;
        _Float16* xp   = (_Float16*)sb;
        _Float16* hp0a = (_Float16*)(sb + XSB);
        _Float16* hp0b = (_Float16*)(sb + XSB + HSB);
        _Float16* hp1a = (_Float16*)(sb + XSB + 2 * HSB);
        _Float16* hp1b = (_Float16*)(sb + XSB + 3 * HSB);
        float*    c0   = (float*)(sb + XSB + 4 * HSB);
        float*    c1   = c0 + CSZ;

        auto convw = [&](const float* s, _Float16* d, int K, int ks3) {
            int total = 4096 * (K >> 3);
            conv_wf16_k<<<dim3(total / 256), blk, 0, stream>>>(s, d, K, ks3);
        };
        convw(Wih0, Wih0f, 128, 4);
        convw(Whh0, Whh0f, 1024, 7);
        convw(Wih1, Wih1f, 1024, 7);
        convw(Whh1, Whh1f, 1024, 7);
        convw(dWih,  dWih0f, 1024, 7);
        convw(dWih1, dWih1f, 1024, 7);
        convw(dWhh,  dWhh0f, 1024, 7);
        convw(dWhh1, dWhh1f, 1024, 7);
        {
            int total8 = BATCH * SEQ * 16;           // x: rows 32768, K=128
            conv_xf16_k<<<dim3((total8 + 255) / 256), blk, 0, stream>>>(x, xp, total8);
        }

        hipMemsetAsync(hp0a, 0, 4 * HSB + 2 * CSZ * 4, stream);

        dim3 fgrid(512);
        _Float16 *hc = hp0a, *hn = hp0b, *h1c = hp1a, *h1n = hp1b;
        const long long XROW = (long long)(SEQ * 128 * 2);  // x row bytes
        for (int t = 0; t < SEQ; ++t) {
            lstm_fs<<<fgrid, blk, 0, stream>>>(
                (const char*)xp + (size_t)t * 256, XROW, DIN,
                (const char*)hc, Wih0f, Whh0f, b0, c0, hn);
            lstm_fs<<<fgrid, blk, 0, stream>>>(
                (const char*)hn, 2048LL, H1,
                (const char*)h1c, Wih1f, Whh1f, b1, c1, h1n);
            _Float16* t0 = hc; hc = hn; hn = t0;
            _Float16* t1 = h1c; h1c = h1n; h1n = t1;
        }
        for (int s = 0; s < TDEC; ++s) {
            lstm_fs<<<fgrid, blk, 0, stream>>>(
                (const char*)h1c, 2048LL, H1,
                (const char*)hc, dWih0f, dWhh0f, db, c0, hn);
            lstm_fs<<<fgrid, blk, 0, stream>>>(
                (const char*)hn, 2048LL, H1,
                (const char*)h1c, dWih1f, dWhh1f, db + FOURH, c1, h1n);
            _Float16* t0 = hc; hc = hn; hn = t0;
            _Float16* t1 = h1c; h1c = h1n; h1n = t1;
        }
        head_fs_k<<<dim3(512), blk, 0, stream>>>(h1c, Wout, bout, (float*)d_out);
    } else {
        // ---------------- f32 fallback (proven) ----------------
        float* h0a = (float*)d_ws;
        float* h0b = h0a + CSZ;
        float* h1a = h0b + CSZ;
        float* h1b = h1a + CSZ;
        float* c0  = h1b + CSZ;
        float* c1  = c0 + CSZ;
        hipMemsetAsync(h0a, 0, 6 * CSZ * 4, stream);

        (void)hipFuncSetAttribute(reinterpret_cast<const void*>(&lstm_fused_f32),
                                  hipFuncAttributeMaxDynamicSharedMemorySize, 147456);

        dim3 oldgrid(256);
        float *hc = h0a, *hn = h0b, *h1c = h1a, *h1n = h1b;
        for (int t = 0; t < SEQ; ++t) {
            lstm_fused_f32<<<oldgrid, blk, 147456, stream>>>(
                x + (size_t)t * DIN, (long long)(SEQ * DIN * 4), DIN, Wih0,
                hc, Whh0, b0, c0, hn);
            lstm_fused_f32<<<oldgrid, blk, 147456, stream>>>(
                hn, 4096LL, H1, Wih1, h1c, Whh1, b1, c1, h1n);
            float* t0 = hc; hc = hn; hn = t0;
            float* t1 = h1c; h1c = h1n; h1n = t1;
        }
        for (int s = 0; s < TDEC; ++s) {
            lstm_fused_f32<<<oldgrid, blk, 147456, stream>>>(
                h1c, 4096LL, H1, dWih, hc, dWhh, db, c0, hn);
            lstm_fused_f32<<<oldgrid, blk, 147456, stream>>>(
                hn, 4096LL, H1, dWih1, h1c, dWhh1, db + FOURH, c1, h1n);
            float* t0 = hc; hc = hn; hn = t0;
            float* t1 = h1c; h1c = h1n; h1n = t1;
        }
        head_k<<<dim3(32), blk, 0, stream>>>(h1c, Wout, bout, (float*)d_out);
    }
}